// Round 1
// baseline (2698.895 us; speedup 1.0000x reference)
//
#include <hip/hip_runtime.h>
#include <hip/hip_bf16.h>
#include <cstdint>

// Problem constants
#define PB 4
#define PS 2048
#define PE 1024
#define PH 16
#define PD 64
#define PM (PB * PS)      // 8192 rows

// ---------------------------------------------------------------------------
// Generic NT GEMM: C = A(MxK,row) . Bw(NxK,row)^T + bias, fp32.
// MODE 0: C[m*N+n]            (optional RELU)
// MODE 1: C at BHSD-permuted index (QKV projection output)
// MODE 2: neuromod combine epilogue:
//         C[m*N+n] = (attn[bhsd]*asc + abi) * (1 + (acc+bias)*gain)
// Tiling: 64x64 tile, 256 threads, 4x4 microtile, TK=32, K-major LDS.
// ---------------------------------------------------------------------------
constexpr int TM = 64, TN = 64, TK = 32, LDT = 68;  // LDT pad -> conflict-free

template<int MODE, bool RELU>
__global__ __launch_bounds__(256)
void gemm_nt(const float* __restrict__ A, const float* __restrict__ Bw,
             const float* __restrict__ bias, float* __restrict__ C,
             int M, int N, int K,
             const float* __restrict__ attn,
             const float* __restrict__ g0, const float* __restrict__ g1,
             const float* __restrict__ g2, const float* __restrict__ g3,
             const float* __restrict__ asc, const float* __restrict__ abi)
{
    __shared__ float As[TK][LDT];
    __shared__ float Bs[TK][LDT];
    const int tid = threadIdx.x;
    const int tx = tid & 15, ty = tid >> 4;
    const int m0 = blockIdx.x * TM, n0 = blockIdx.y * TN;

    float acc[4][4] = {};

    for (int k0 = 0; k0 < K; k0 += TK) {
        // Stage 64 rows x 32 K of A and Bw, transposed to K-major in LDS.
        #pragma unroll
        for (int rep = 0; rep < 2; ++rep) {
            int i   = tid + 256 * rep;     // f4 index 0..511
            int row = i >> 3;              // 0..63
            int kc  = (i & 7) << 2;        // 0,4,...,28
            float4 fa = *(const float4*)&A [(size_t)(m0 + row) * K + k0 + kc];
            float4 fb = *(const float4*)&Bw[(size_t)(n0 + row) * K + k0 + kc];
            As[kc + 0][row] = fa.x; As[kc + 1][row] = fa.y;
            As[kc + 2][row] = fa.z; As[kc + 3][row] = fa.w;
            Bs[kc + 0][row] = fb.x; Bs[kc + 1][row] = fb.y;
            Bs[kc + 2][row] = fb.z; Bs[kc + 3][row] = fb.w;
        }
        __syncthreads();
        #pragma unroll
        for (int kk = 0; kk < TK; ++kk) {
            float4 a = *(const float4*)&As[kk][ty << 2];
            float4 b = *(const float4*)&Bs[kk][tx << 2];
            acc[0][0] += a.x * b.x; acc[0][1] += a.x * b.y;
            acc[0][2] += a.x * b.z; acc[0][3] += a.x * b.w;
            acc[1][0] += a.y * b.x; acc[1][1] += a.y * b.y;
            acc[1][2] += a.y * b.z; acc[1][3] += a.y * b.w;
            acc[2][0] += a.z * b.x; acc[2][1] += a.z * b.y;
            acc[2][2] += a.z * b.z; acc[2][3] += a.z * b.w;
            acc[3][0] += a.w * b.x; acc[3][1] += a.w * b.y;
            acc[3][2] += a.w * b.z; acc[3][3] += a.w * b.w;
        }
        __syncthreads();
    }

    float gain = 0.f, ascv = 0.f, abiv = 0.f;
    if (MODE == 2) {
        gain = 0.25f * (*g0 + *g1 + *g2 + *g3);
        ascv = *asc;
        abiv = *abi;
    }

    const int c0 = n0 + (tx << 2);
    #pragma unroll
    for (int i = 0; i < 4; ++i) {
        const int r = m0 + (ty << 2) + i;
        float v0 = acc[i][0] + bias[c0 + 0];
        float v1 = acc[i][1] + bias[c0 + 1];
        float v2 = acc[i][2] + bias[c0 + 2];
        float v3 = acc[i][3] + bias[c0 + 3];
        if (RELU) {
            v0 = fmaxf(v0, 0.f); v1 = fmaxf(v1, 0.f);
            v2 = fmaxf(v2, 0.f); v3 = fmaxf(v3, 0.f);
        }
        if (MODE == 0) {
            float4 v = make_float4(v0, v1, v2, v3);
            *(float4*)&C[(size_t)r * N + c0] = v;
        } else if (MODE == 1) {
            // (b,s) = row, (h,d) = col ; out[((b*H+h)*S+s)*D+d]
            int b = r >> 11, s = r & 2047;
            int h = c0 >> 6, d = c0 & 63;
            size_t idx = ((size_t)(b * PH + h) * PS + s) * PD + d;
            *(float4*)&C[idx] = make_float4(v0, v1, v2, v3);
        } else {
            int b = r >> 11, s = r & 2047;
            int h = c0 >> 6, d = c0 & 63;
            size_t idx = ((size_t)(b * PH + h) * PS + s) * PD + d;
            float4 av = *(const float4*)&attn[idx];
            float4 o;
            o.x = (av.x * ascv + abiv) * (1.f + v0 * gain);
            o.y = (av.y * ascv + abiv) * (1.f + v1 * gain);
            o.z = (av.z * ascv + abiv) * (1.f + v2 * gain);
            o.w = (av.w * ascv + abiv) * (1.f + v3 * gain);
            *(float4*)&C[(size_t)r * N + c0] = o;
        }
    }
}

// ---------------------------------------------------------------------------
// Flash attention, fp32. One q-row per thread (q,o in registers).
// K/V staged in LDS per 64-row tile. Lazy-rescale online softmax.
// Writes attn output OVER the q buffer (same rows: read-before-write safe).
// ---------------------------------------------------------------------------
__global__ __launch_bounds__(256)
void flash_attn(const float* __restrict__ qg, const float* __restrict__ kg,
                const float* __restrict__ vg, float* __restrict__ og)
{
    __shared__ float Ks[64][64];
    __shared__ float Vs[64][64];
    const int tid = threadIdx.x;
    const int bh  = blockIdx.z * PH + blockIdx.y;
    const size_t base = (size_t)bh * (PS * PD);
    const int row = blockIdx.x * 256 + tid;

    float4 qv[16];
    {
        const float4* qp = (const float4*)&qg[base + (size_t)row * PD];
        #pragma unroll
        for (int i = 0; i < 16; ++i) qv[i] = qp[i];
    }
    float4 ov[16];
    #pragma unroll
    for (int i = 0; i < 16; ++i) ov[i] = make_float4(0.f, 0.f, 0.f, 0.f);
    float mrun = -__builtin_inff();
    float lrun = 0.f;

    for (int kt = 0; kt < PS; kt += 64) {
        __syncthreads();
        #pragma unroll
        for (int rep = 0; rep < 4; ++rep) {
            int i  = tid + 256 * rep;   // f4 index 0..1023
            int kr = i >> 4;            // 0..63
            int kc = (i & 15) << 2;     // 0..60
            *(float4*)&Ks[kr][kc] = *(const float4*)&kg[base + (size_t)(kt + kr) * PD + kc];
            *(float4*)&Vs[kr][kc] = *(const float4*)&vg[base + (size_t)(kt + kr) * PD + kc];
        }
        __syncthreads();

        for (int r = 0; r < 64; ++r) {
            const float4* kp = (const float4*)&Ks[r][0];
            float4 sa = make_float4(0.f, 0.f, 0.f, 0.f);
            #pragma unroll
            for (int i = 0; i < 16; ++i) {
                float4 kk = kp[i];
                sa.x += qv[i].x * kk.x;
                sa.y += qv[i].y * kk.y;
                sa.z += qv[i].z * kk.z;
                sa.w += qv[i].w * kk.w;
            }
            float s = ((sa.x + sa.y) + (sa.z + sa.w)) * 0.125f;  // * D^-0.5

            if (s > mrun) {                       // rare: ~log(S) times/thread
                float cfac = __expf(mrun - s);
                mrun = s;
                lrun *= cfac;
                #pragma unroll
                for (int i = 0; i < 16; ++i) {
                    ov[i].x *= cfac; ov[i].y *= cfac;
                    ov[i].z *= cfac; ov[i].w *= cfac;
                }
            }
            float p = __expf(s - mrun);
            lrun += p;
            const float4* vp = (const float4*)&Vs[r][0];
            #pragma unroll
            for (int i = 0; i < 16; ++i) {
                float4 vv = vp[i];
                ov[i].x += p * vv.x; ov[i].y += p * vv.y;
                ov[i].z += p * vv.z; ov[i].w += p * vv.w;
            }
        }
    }

    const float inv = 1.f / lrun;
    float4* op = (float4*)&og[base + (size_t)row * PD];
    #pragma unroll
    for (int i = 0; i < 16; ++i)
        op[i] = make_float4(ov[i].x * inv, ov[i].y * inv, ov[i].z * inv, ov[i].w * inv);
}

// ---------------------------------------------------------------------------
extern "C" void kernel_launch(void* const* d_in, const int* in_sizes, int n_in,
                              void* d_out, int out_size, void* d_ws, size_t ws_size,
                              hipStream_t stream)
{
    const float* query = (const float*)d_in[0];
    const float* Wq  = (const float*)d_in[1];  const float* bq  = (const float*)d_in[2];
    const float* Wk  = (const float*)d_in[3];  const float* bk  = (const float*)d_in[4];
    const float* Wv  = (const float*)d_in[5];  const float* bv  = (const float*)d_in[6];
    const float* Wo  = (const float*)d_in[7];  const float* bo  = (const float*)d_in[8];
    const float* Wm1 = (const float*)d_in[9];  const float* bm1 = (const float*)d_in[10];
    const float* Wm2 = (const float*)d_in[11]; const float* bm2 = (const float*)d_in[12];
    const float* dop = (const float*)d_in[13];
    const float* ser = (const float*)d_in[14];
    const float* nor = (const float*)d_in[15];
    const float* ach = (const float*)d_in[16];
    const float* asc = (const float*)d_in[17];
    const float* abi = (const float*)d_in[18];
    float* out = (float*)d_out;

    // Workspace layout (floats). attn reuses q; attnf reuses k.
    float* ws   = (float*)d_ws;
    float* qb   = ws;                    // [B,H,S,D] 8388608 f  (later: attn)
    float* kb   = ws + 8388608;          // [B,H,S,D] 8388608 f  (later: attnf)
    float* vb   = ws + 16777216;         // [B,H,S,D] 8388608 f
    float* h1   = ws + 25165824;         // [M,256]   2097152 f

    dim3 blk(256);

    // Q/K/V projections: [8192,1024] x [1024,1024]^T -> BHSD
    gemm_nt<1, false><<<dim3(PM / TM, PE / TN), blk, 0, stream>>>(
        query, Wq, bq, qb, PM, PE, PE,
        nullptr, nullptr, nullptr, nullptr, nullptr, nullptr, nullptr);
    gemm_nt<1, false><<<dim3(PM / TM, PE / TN), blk, 0, stream>>>(
        query, Wk, bk, kb, PM, PE, PE,
        nullptr, nullptr, nullptr, nullptr, nullptr, nullptr, nullptr);
    gemm_nt<1, false><<<dim3(PM / TM, PE / TN), blk, 0, stream>>>(
        query, Wv, bv, vb, PM, PE, PE,
        nullptr, nullptr, nullptr, nullptr, nullptr, nullptr, nullptr);

    // Attention: writes attn over qb
    flash_attn<<<dim3(PS / 256, PH, PB), blk, 0, stream>>>(qb, kb, vb, qb);

    // MLP layer 1: h1 = relu(query @ Wm1^T + bm1)  [8192,256], K=1024
    gemm_nt<0, true><<<dim3(PM / TM, 256 / TN), blk, 0, stream>>>(
        query, Wm1, bm1, h1, PM, 256, PE,
        nullptr, nullptr, nullptr, nullptr, nullptr, nullptr, nullptr);

    // MLP layer 2 + neuromod combine: attnf (over kb), K=256
    gemm_nt<2, false><<<dim3(PM / TM, PE / TN), blk, 0, stream>>>(
        h1, Wm2, bm2, kb, PM, PE, 256,
        qb, dop, ser, nor, ach, asc, abi);

    // Output projection: out = attnf @ Wo^T + bo
    gemm_nt<0, false><<<dim3(PM / TM, PE / TN), blk, 0, stream>>>(
        kb, Wo, bo, out, PM, PE, PE,
        nullptr, nullptr, nullptr, nullptr, nullptr, nullptr, nullptr);
}

// Round 3
// 2199.084 us; speedup vs baseline: 1.2273x; 1.2273x over previous
//
#include <hip/hip_runtime.h>
#include <hip/hip_bf16.h>
#include <cstdint>

// Problem constants
#define PB 4
#define PS 2048
#define PE 1024
#define PH 16
#define PD 64
#define PM (PB * PS)      // 8192 rows

typedef __attribute__((ext_vector_type(8))) short short8;   // 8 bf16 (4 VGPR)
typedef __attribute__((ext_vector_type(4))) float f32x4;

#define MFMA16 __builtin_amdgcn_mfma_f32_16x16x32_bf16

// fp32 -> bf16 round-to-nearest-even (finite inputs)
__device__ inline unsigned short bf16rn(float x) {
    unsigned u = __builtin_bit_cast(unsigned, x);
    u += 0x7FFFu + ((u >> 16) & 1u);
    return (unsigned short)(u >> 16);
}
__device__ inline float bf16tof(unsigned short h) {
    unsigned u = ((unsigned)h) << 16;
    return __builtin_bit_cast(float, u);
}
__device__ inline void split2(float x, unsigned short& h, unsigned short& l) {
    h = bf16rn(x);
    l = bf16rn(x - bf16tof(h));
}

// ---------------------------------------------------------------------------
// Generic NT GEMM: C = A(MxK,row) . Bw(NxK,row)^T + bias, fp32 vector ALU.
// MODE 0: C[m*N+n]                     (optional RELU)
// MODE 1: fp32 at BHSD-permuted index  (Q projection)
// MODE 2: neuromod combine epilogue -> fp32 C
// MODE 3: bf16 hi/lo planes at BHSD index      (K projection)
// MODE 4: bf16 hi/lo planes at BHDS (V^T) index with the PV sequence
//         permutation applied within each 64-tile (see flash_mfma).
// ---------------------------------------------------------------------------
constexpr int TM = 64, TN = 64, TK = 32, LDT = 68;

template<int MODE, bool RELU>
__global__ __launch_bounds__(256)
void gemm_nt(const float* __restrict__ A, const float* __restrict__ Bw,
             const float* __restrict__ bias, float* __restrict__ C,
             unsigned short* __restrict__ Ohi, unsigned short* __restrict__ Olo,
             int M, int N, int K,
             const float* __restrict__ attn,
             const float* __restrict__ g0, const float* __restrict__ g1,
             const float* __restrict__ g2, const float* __restrict__ g3,
             const float* __restrict__ asc, const float* __restrict__ abi)
{
    __shared__ float As[TK][LDT];
    __shared__ float Bs[TK][LDT];
    const int tid = threadIdx.x;
    const int tx = tid & 15, ty = tid >> 4;
    const int m0 = blockIdx.x * TM, n0 = blockIdx.y * TN;

    float acc[4][4] = {};

    for (int k0 = 0; k0 < K; k0 += TK) {
        #pragma unroll
        for (int rep = 0; rep < 2; ++rep) {
            int i   = tid + 256 * rep;
            int row = i >> 3;
            int kc  = (i & 7) << 2;
            float4 fa = *(const float4*)&A [(size_t)(m0 + row) * K + k0 + kc];
            float4 fb = *(const float4*)&Bw[(size_t)(n0 + row) * K + k0 + kc];
            As[kc + 0][row] = fa.x; As[kc + 1][row] = fa.y;
            As[kc + 2][row] = fa.z; As[kc + 3][row] = fa.w;
            Bs[kc + 0][row] = fb.x; Bs[kc + 1][row] = fb.y;
            Bs[kc + 2][row] = fb.z; Bs[kc + 3][row] = fb.w;
        }
        __syncthreads();
        #pragma unroll
        for (int kk = 0; kk < TK; ++kk) {
            float4 a = *(const float4*)&As[kk][ty << 2];
            float4 b = *(const float4*)&Bs[kk][tx << 2];
            acc[0][0] += a.x * b.x; acc[0][1] += a.x * b.y;
            acc[0][2] += a.x * b.z; acc[0][3] += a.x * b.w;
            acc[1][0] += a.y * b.x; acc[1][1] += a.y * b.y;
            acc[1][2] += a.y * b.z; acc[1][3] += a.y * b.w;
            acc[2][0] += a.z * b.x; acc[2][1] += a.z * b.y;
            acc[2][2] += a.z * b.z; acc[2][3] += a.z * b.w;
            acc[3][0] += a.w * b.x; acc[3][1] += a.w * b.y;
            acc[3][2] += a.w * b.z; acc[3][3] += a.w * b.w;
        }
        __syncthreads();
    }

    float gain = 0.f, ascv = 0.f, abiv = 0.f;
    if (MODE == 2) {
        gain = 0.25f * (*g0 + *g1 + *g2 + *g3);
        ascv = *asc;
        abiv = *abi;
    }

    const int c0 = n0 + (tx << 2);

    if (MODE == 4) {
        // V^T write with PV permutation: true in-tile row r = 16mt+4lg+j
        // is stored at column c = 32*(mt&1) + 8*lg + ((mt>>1)<<2 | j).
        const int r0 = m0 + (ty << 2);
        const int bb = r0 >> 11, s0 = r0 & 2047;
        const int h = c0 >> 6, d0 = c0 & 63;
        const int rl  = s0 & 63;                 // 4-aligned in-tile row
        const int mtP = rl >> 4, lgP = (rl >> 2) & 3;
        const int scol = (s0 & ~63) + ((mtP & 1) << 5) + (lgP << 3)
                       + ((mtP >> 1) << 2);      // j=0..3 -> consecutive
        #pragma unroll
        for (int c = 0; c < 4; ++c) {
            const float bv = bias[c0 + c];
            unsigned short h0, l0, h1v, l1, h2, l2, h3, l3;
            split2(acc[0][c] + bv, h0, l0);
            split2(acc[1][c] + bv, h1v, l1);
            split2(acc[2][c] + bv, h2, l2);
            split2(acc[3][c] + bv, h3, l3);
            size_t idx = ((size_t)(bb * PH + h) * PD + d0 + c) * PS + scol;
            ushort4 hv; hv.x = h0; hv.y = h1v; hv.z = h2; hv.w = h3;
            ushort4 lv; lv.x = l0; lv.y = l1;  lv.z = l2; lv.w = l3;
            *(ushort4*)&Ohi[idx] = hv;
            *(ushort4*)&Olo[idx] = lv;
        }
        return;
    }

    #pragma unroll
    for (int i = 0; i < 4; ++i) {
        const int r = m0 + (ty << 2) + i;
        float v0 = acc[i][0] + bias[c0 + 0];
        float v1 = acc[i][1] + bias[c0 + 1];
        float v2 = acc[i][2] + bias[c0 + 2];
        float v3 = acc[i][3] + bias[c0 + 3];
        if (RELU) {
            v0 = fmaxf(v0, 0.f); v1 = fmaxf(v1, 0.f);
            v2 = fmaxf(v2, 0.f); v3 = fmaxf(v3, 0.f);
        }
        if (MODE == 0) {
            *(float4*)&C[(size_t)r * N + c0] = make_float4(v0, v1, v2, v3);
        } else if (MODE == 1) {
            int b = r >> 11, s = r & 2047;
            int h = c0 >> 6, d = c0 & 63;
            size_t idx = ((size_t)(b * PH + h) * PS + s) * PD + d;
            *(float4*)&C[idx] = make_float4(v0, v1, v2, v3);
        } else if (MODE == 3) {
            int b = r >> 11, s = r & 2047;
            int h = c0 >> 6, d = c0 & 63;
            size_t idx = ((size_t)(b * PH + h) * PS + s) * PD + d;
            unsigned short h0, l0, h1v, l1, h2, l2, h3, l3;
            split2(v0, h0, l0); split2(v1, h1v, l1);
            split2(v2, h2, l2); split2(v3, h3, l3);
            ushort4 hv; hv.x = h0; hv.y = h1v; hv.z = h2; hv.w = h3;
            ushort4 lv; lv.x = l0; lv.y = l1;  lv.z = l2; lv.w = l3;
            *(ushort4*)&Ohi[idx] = hv;
            *(ushort4*)&Olo[idx] = lv;
        } else { // MODE 2
            int b = r >> 11, s = r & 2047;
            int h = c0 >> 6, d = c0 & 63;
            size_t idx = ((size_t)(b * PH + h) * PS + s) * PD + d;
            float4 av = *(const float4*)&attn[idx];
            float4 o;
            o.x = (av.x * ascv + abiv) * (1.f + v0 * gain);
            o.y = (av.y * ascv + abiv) * (1.f + v1 * gain);
            o.z = (av.z * ascv + abiv) * (1.f + v2 * gain);
            o.w = (av.w * ascv + abiv) * (1.f + v3 * gain);
            *(float4*)&C[(size_t)r * N + c0] = o;
        }
    }
}

// ---------------------------------------------------------------------------
// MFMA flash attention, split-bf16 (hi/lo) compensated products.
// Swapped operands: S^T = K . Q^T (lane owns one q-column). PV as
// O^T = V^T . P^T where V^T is stored sequence-PERMUTED within each
// 64-tile so the P^T B-fragments are exactly the lane's own register
// values (no cross-lane traffic):
//   lane(lq,lg) holds P_stored[16mt+4lg+j][lq]; the t-th PV MFMA needs
//   B[k=8lg+b][lq] = value for V^T column 32t+8lg+b, whose stored true
//   row is 16*((b>>2)*2+t)+4lg+(b&3)  =>  frag[b] = p[(b>>2)*2+t][b&3].
// 4 independent waves / block, 16 q rows each. No LDS, no barriers.
// attn output overwrites the q buffer (same rows, read-before-write).
// ---------------------------------------------------------------------------
__global__ __launch_bounds__(256)
void flash_mfma(const float* qf,
                const unsigned short* __restrict__ khi,
                const unsigned short* __restrict__ klo,
                const unsigned short* __restrict__ vthi,
                const unsigned short* __restrict__ vtlo,
                float* attn)
{
    const int lane = threadIdx.x & 63;
    const int w    = threadIdx.x >> 6;
    const int bh   = blockIdx.z * PH + blockIdx.y;
    const int q0   = blockIdx.x * 64 + w * 16;
    const int lq   = lane & 15;
    const int lg   = lane >> 4;

    // Q fragments (B-operand): B[k=d][j=q], j=lq, d = 8*lg + b + 32*t.
    // Fold the 1/sqrt(D) score scale into q here (1/8, exact).
    const float* qp = qf + ((size_t)bh * PS + q0 + lq) * PD + 8 * lg;
    short8 qh[2], ql[2];
    #pragma unroll
    for (int t = 0; t < 2; ++t) {
        #pragma unroll
        for (int b = 0; b < 8; ++b) {
            float x = qp[t * 32 + b] * 0.125f;
            unsigned short h, l;
            split2(x, h, l);
            qh[t][b] = (short)h;
            ql[t][b] = (short)l;
        }
    }

    f32x4 ot[4] = {{0.f,0.f,0.f,0.f},{0.f,0.f,0.f,0.f},
                   {0.f,0.f,0.f,0.f},{0.f,0.f,0.f,0.f}};
    float m_run = -3.0e38f, l_run = 0.f;

    const size_t kbase = (size_t)bh * PS * PD;   // K rows   [S][D]
    const size_t vbase = (size_t)bh * PD * PS;   // V^T rows [D][S] (permuted)

    for (int kt = 0; kt < PS; kt += 64) {
        // ---- S^T tile = K . Q^T : lane holds st[mt][j] =
        //      S^T[kt + 16mt + 4lg + j][q0 + lq]
        f32x4 st[4];
        #pragma unroll
        for (int mt = 0; mt < 4; ++mt) {
            size_t ko = kbase + (size_t)(kt + 16 * mt + lq) * PD + 8 * lg;
            short8 ah0 = *(const short8*)(khi + ko);
            short8 ah1 = *(const short8*)(khi + ko + 32);
            short8 al0 = *(const short8*)(klo + ko);
            short8 al1 = *(const short8*)(klo + ko + 32);
            f32x4 acc = {0.f, 0.f, 0.f, 0.f};
            acc = MFMA16(ah0, qh[0], acc, 0, 0, 0);
            acc = MFMA16(ah1, qh[1], acc, 0, 0, 0);
            acc = MFMA16(ah0, ql[0], acc, 0, 0, 0);
            acc = MFMA16(ah1, ql[1], acc, 0, 0, 0);
            acc = MFMA16(al0, qh[0], acc, 0, 0, 0);
            acc = MFMA16(al1, qh[1], acc, 0, 0, 0);
            st[mt] = acc;
        }

        // ---- online softmax over kk for this lane's q column
        float pmax = -3.0e38f;
        #pragma unroll
        for (int mt = 0; mt < 4; ++mt)
            #pragma unroll
            for (int j = 0; j < 4; ++j)
                pmax = fmaxf(pmax, st[mt][j]);
        pmax = fmaxf(pmax, __shfl_xor(pmax, 16));
        pmax = fmaxf(pmax, __shfl_xor(pmax, 32));
        float mnew = fmaxf(m_run, pmax);
        float corr = __expf(m_run - mnew);
        float psum = 0.f;
        #pragma unroll
        for (int mt = 0; mt < 4; ++mt)
            #pragma unroll
            for (int j = 0; j < 4; ++j) {
                float p = __expf(st[mt][j] - mnew);
                psum += p;
                st[mt][j] = p;           // st now holds P
            }
        psum += __shfl_xor(psum, 16);
        psum += __shfl_xor(psum, 32);
        l_run = l_run * corr + psum;
        m_run = mnew;
        #pragma unroll
        for (int mt = 0; mt < 4; ++mt)
            #pragma unroll
            for (int j = 0; j < 4; ++j)
                ot[mt][j] *= corr;

        // ---- P^T B-fragments straight from registers (permuted V^T)
        short8 pbh[2], pbl[2];
        #pragma unroll
        for (int b = 0; b < 8; ++b) {
            const int mt0 = (b >> 2) << 1;
            unsigned short h0, l0, h1, l1;
            split2(st[mt0][b & 3], h0, l0);
            split2(st[mt0 + 1][b & 3], h1, l1);
            pbh[0][b] = (short)h0; pbl[0][b] = (short)l0;
            pbh[1][b] = (short)h1; pbl[1][b] = (short)l1;
        }

        // ---- O^T += V^T . P^T
        #pragma unroll
        for (int t = 0; t < 2; ++t) {
            #pragma unroll
            for (int mt = 0; mt < 4; ++mt) {
                size_t vo = vbase + (size_t)(16 * mt + lq) * PS + kt + 32 * t + 8 * lg;
                short8 vh = *(const short8*)(vthi + vo);
                short8 vl = *(const short8*)(vtlo + vo);
                ot[mt] = MFMA16(vh, pbh[t], ot[mt], 0, 0, 0);
                ot[mt] = MFMA16(vh, pbl[t], ot[mt], 0, 0, 0);
                ot[mt] = MFMA16(vl, pbh[t], ot[mt], 0, 0, 0);
            }
        }
    }

    // ---- epilogue: attn[bh][q0+lq][d], d = 16*mt + 4*lg + j
    const float inv = 1.f / l_run;
    float* op = attn + ((size_t)bh * PS + q0 + lq) * PD + 4 * lg;
    #pragma unroll
    for (int mt = 0; mt < 4; ++mt) {
        float4 o;
        o.x = ot[mt][0] * inv; o.y = ot[mt][1] * inv;
        o.z = ot[mt][2] * inv; o.w = ot[mt][3] * inv;
        *(float4*)(op + 16 * mt) = o;
    }
}

// ---------------------------------------------------------------------------
extern "C" void kernel_launch(void* const* d_in, const int* in_sizes, int n_in,
                              void* d_out, int out_size, void* d_ws, size_t ws_size,
                              hipStream_t stream)
{
    const float* query = (const float*)d_in[0];
    const float* Wq  = (const float*)d_in[1];  const float* bq  = (const float*)d_in[2];
    const float* Wk  = (const float*)d_in[3];  const float* bk  = (const float*)d_in[4];
    const float* Wv  = (const float*)d_in[5];  const float* bv  = (const float*)d_in[6];
    const float* Wo  = (const float*)d_in[7];  const float* bo  = (const float*)d_in[8];
    const float* Wm1 = (const float*)d_in[9];  const float* bm1 = (const float*)d_in[10];
    const float* Wm2 = (const float*)d_in[11]; const float* bm2 = (const float*)d_in[12];
    const float* dop = (const float*)d_in[13];
    const float* ser = (const float*)d_in[14];
    const float* nor = (const float*)d_in[15];
    const float* ach = (const float*)d_in[16];
    const float* asc = (const float*)d_in[17];
    const float* abi = (const float*)d_in[18];
    float* out = (float*)d_out;

    // Workspace (104 MB):
    //  [  0MB, 32MB)  qf32 [B,H,S,D]   -> attn overwrites it in flash_mfma
    //  [ 32MB, 64MB)  khi,klo bf16 planes -> attnf fp32 overlays after attn
    //  [ 64MB, 96MB)  vthi,vtlo bf16 planes (V^T: [B,H,D,S], seq-permuted)
    //  [ 96MB,104MB)  h1 fp32 [M,256]
    float* ws = (float*)d_ws;
    float*          qf32  = ws;                                   // 8388608 f
    unsigned short* khi   = (unsigned short*)(ws + 8388608);      // 8388608 us
    unsigned short* klo   = khi + 8388608;
    unsigned short* vthi  = (unsigned short*)(ws + 16777216);
    unsigned short* vtlo  = vthi + 8388608;
    float*          h1    = ws + 25165824;                        // 2097152 f
    float*          attnf = ws + 8388608;                         // over k planes

    dim3 blk(256);

    // Projections
    gemm_nt<1, false><<<dim3(PM / TM, PE / TN), blk, 0, stream>>>(
        query, Wq, bq, qf32, nullptr, nullptr, PM, PE, PE,
        nullptr, nullptr, nullptr, nullptr, nullptr, nullptr, nullptr);
    gemm_nt<3, false><<<dim3(PM / TM, PE / TN), blk, 0, stream>>>(
        query, Wk, bk, nullptr, khi, klo, PM, PE, PE,
        nullptr, nullptr, nullptr, nullptr, nullptr, nullptr, nullptr);
    gemm_nt<4, false><<<dim3(PM / TM, PE / TN), blk, 0, stream>>>(
        query, Wv, bv, nullptr, vthi, vtlo, PM, PE, PE,
        nullptr, nullptr, nullptr, nullptr, nullptr, nullptr, nullptr);

    // MLP layer 1 (fp32): h1 = relu(query @ Wm1^T + bm1)
    gemm_nt<0, true><<<dim3(PM / TM, 256 / TN), blk, 0, stream>>>(
        query, Wm1, bm1, h1, nullptr, nullptr, PM, 256, PE,
        nullptr, nullptr, nullptr, nullptr, nullptr, nullptr, nullptr);

    // Flash attention (attn -> over qf32)
    flash_mfma<<<dim3(PS / 64, PH, PB), blk, 0, stream>>>(
        qf32, khi, klo, vthi, vtlo, qf32);

    // MLP layer 2 + neuromod combine: attnf (over k planes)
    gemm_nt<2, false><<<dim3(PM / TM, PE / TN), blk, 0, stream>>>(
        h1, Wm2, bm2, attnf, nullptr, nullptr, PM, PE, 256,
        qf32, dop, ser, nor, ach, asc, abi);

    // Output projection
    gemm_nt<0, false><<<dim3(PM / TM, PE / TN), blk, 0, stream>>>(
        attnf, Wo, bo, out, nullptr, nullptr, PM, PE, PE,
        nullptr, nullptr, nullptr, nullptr, nullptr, nullptr, nullptr);
}

// Round 4
// 1549.105 us; speedup vs baseline: 1.7422x; 1.4196x over previous
//
#include <hip/hip_runtime.h>
#include <hip/hip_bf16.h>
#include <cstdint>

// Problem constants
#define PB 4
#define PS 2048
#define PE 1024
#define PH 16
#define PD 64
#define PM (PB * PS)      // 8192 rows

typedef __attribute__((ext_vector_type(8))) short short8;   // 8 bf16 (4 VGPR)
typedef __attribute__((ext_vector_type(4))) float f32x4;

#define MFMA16 __builtin_amdgcn_mfma_f32_16x16x32_bf16

// fp32 -> bf16 round-to-nearest-even (finite inputs)
__device__ inline unsigned short bf16rn(float x) {
    unsigned u = __builtin_bit_cast(unsigned, x);
    u += 0x7FFFu + ((u >> 16) & 1u);
    return (unsigned short)(u >> 16);
}
__device__ inline float bf16tof(unsigned short h) {
    unsigned u = ((unsigned)h) << 16;
    return __builtin_bit_cast(float, u);
}
__device__ inline void split2(float x, unsigned short& h, unsigned short& l) {
    h = bf16rn(x);
    l = bf16rn(x - bf16tof(h));
}

// ---------------------------------------------------------------------------
// Generic NT GEMM: C = A(MxK,row) . Bw(NxK,row)^T + bias, fp32 vector ALU.
// MODE 0: C[m*N+n]                     (optional RELU)
// MODE 1: fp32 at BHSD-permuted index  (Q projection)
// MODE 2: neuromod combine epilogue -> fp32 C
// MODE 3: bf16 hi/lo planes at BHSD index      (K projection)
// MODE 4: bf16 hi/lo planes at BHDS (V^T) index with the PV sequence
//         permutation applied within each 64-tile (see flash_mfma).
// ---------------------------------------------------------------------------
constexpr int TM = 64, TN = 64, TK = 32, LDT = 68;

template<int MODE, bool RELU>
__global__ __launch_bounds__(256)
void gemm_nt(const float* __restrict__ A, const float* __restrict__ Bw,
             const float* __restrict__ bias, float* __restrict__ C,
             unsigned short* __restrict__ Ohi, unsigned short* __restrict__ Olo,
             int M, int N, int K,
             const float* __restrict__ attn,
             const float* __restrict__ g0, const float* __restrict__ g1,
             const float* __restrict__ g2, const float* __restrict__ g3,
             const float* __restrict__ asc, const float* __restrict__ abi)
{
    __shared__ float As[TK][LDT];
    __shared__ float Bs[TK][LDT];
    const int tid = threadIdx.x;
    const int tx = tid & 15, ty = tid >> 4;
    const int m0 = blockIdx.x * TM, n0 = blockIdx.y * TN;

    float acc[4][4] = {};

    for (int k0 = 0; k0 < K; k0 += TK) {
        #pragma unroll
        for (int rep = 0; rep < 2; ++rep) {
            int i   = tid + 256 * rep;
            int row = i >> 3;
            int kc  = (i & 7) << 2;
            float4 fa = *(const float4*)&A [(size_t)(m0 + row) * K + k0 + kc];
            float4 fb = *(const float4*)&Bw[(size_t)(n0 + row) * K + k0 + kc];
            As[kc + 0][row] = fa.x; As[kc + 1][row] = fa.y;
            As[kc + 2][row] = fa.z; As[kc + 3][row] = fa.w;
            Bs[kc + 0][row] = fb.x; Bs[kc + 1][row] = fb.y;
            Bs[kc + 2][row] = fb.z; Bs[kc + 3][row] = fb.w;
        }
        __syncthreads();
        #pragma unroll
        for (int kk = 0; kk < TK; ++kk) {
            float4 a = *(const float4*)&As[kk][ty << 2];
            float4 b = *(const float4*)&Bs[kk][tx << 2];
            acc[0][0] += a.x * b.x; acc[0][1] += a.x * b.y;
            acc[0][2] += a.x * b.z; acc[0][3] += a.x * b.w;
            acc[1][0] += a.y * b.x; acc[1][1] += a.y * b.y;
            acc[1][2] += a.y * b.z; acc[1][3] += a.y * b.w;
            acc[2][0] += a.z * b.x; acc[2][1] += a.z * b.y;
            acc[2][2] += a.z * b.z; acc[2][3] += a.z * b.w;
            acc[3][0] += a.w * b.x; acc[3][1] += a.w * b.y;
            acc[3][2] += a.w * b.z; acc[3][3] += a.w * b.w;
        }
        __syncthreads();
    }

    float gain = 0.f, ascv = 0.f, abiv = 0.f;
    if (MODE == 2) {
        gain = 0.25f * (*g0 + *g1 + *g2 + *g3);
        ascv = *asc;
        abiv = *abi;
    }

    const int c0 = n0 + (tx << 2);

    if (MODE == 4) {
        // V^T write with PV permutation: true in-tile row r = 16mt+4lg+j
        // is stored at column c = 32*(mt&1) + 8*lg + ((mt>>1)<<2 | j).
        const int r0 = m0 + (ty << 2);
        const int bb = r0 >> 11, s0 = r0 & 2047;
        const int h = c0 >> 6, d0 = c0 & 63;
        const int rl  = s0 & 63;                 // 4-aligned in-tile row
        const int mtP = rl >> 4, lgP = (rl >> 2) & 3;
        const int scol = (s0 & ~63) + ((mtP & 1) << 5) + (lgP << 3)
                       + ((mtP >> 1) << 2);      // j=0..3 -> consecutive
        #pragma unroll
        for (int c = 0; c < 4; ++c) {
            const float bv = bias[c0 + c];
            unsigned short h0, l0, h1v, l1, h2, l2, h3, l3;
            split2(acc[0][c] + bv, h0, l0);
            split2(acc[1][c] + bv, h1v, l1);
            split2(acc[2][c] + bv, h2, l2);
            split2(acc[3][c] + bv, h3, l3);
            size_t idx = ((size_t)(bb * PH + h) * PD + d0 + c) * PS + scol;
            ushort4 hv; hv.x = h0; hv.y = h1v; hv.z = h2; hv.w = h3;
            ushort4 lv; lv.x = l0; lv.y = l1;  lv.z = l2; lv.w = l3;
            *(ushort4*)&Ohi[idx] = hv;
            *(ushort4*)&Olo[idx] = lv;
        }
        return;
    }

    #pragma unroll
    for (int i = 0; i < 4; ++i) {
        const int r = m0 + (ty << 2) + i;
        float v0 = acc[i][0] + bias[c0 + 0];
        float v1 = acc[i][1] + bias[c0 + 1];
        float v2 = acc[i][2] + bias[c0 + 2];
        float v3 = acc[i][3] + bias[c0 + 3];
        if (RELU) {
            v0 = fmaxf(v0, 0.f); v1 = fmaxf(v1, 0.f);
            v2 = fmaxf(v2, 0.f); v3 = fmaxf(v3, 0.f);
        }
        if (MODE == 0) {
            *(float4*)&C[(size_t)r * N + c0] = make_float4(v0, v1, v2, v3);
        } else if (MODE == 1) {
            int b = r >> 11, s = r & 2047;
            int h = c0 >> 6, d = c0 & 63;
            size_t idx = ((size_t)(b * PH + h) * PS + s) * PD + d;
            *(float4*)&C[idx] = make_float4(v0, v1, v2, v3);
        } else if (MODE == 3) {
            int b = r >> 11, s = r & 2047;
            int h = c0 >> 6, d = c0 & 63;
            size_t idx = ((size_t)(b * PH + h) * PS + s) * PD + d;
            unsigned short h0, l0, h1v, l1, h2, l2, h3, l3;
            split2(v0, h0, l0); split2(v1, h1v, l1);
            split2(v2, h2, l2); split2(v3, h3, l3);
            ushort4 hv; hv.x = h0; hv.y = h1v; hv.z = h2; hv.w = h3;
            ushort4 lv; lv.x = l0; lv.y = l1;  lv.z = l2; lv.w = l3;
            *(ushort4*)&Ohi[idx] = hv;
            *(ushort4*)&Olo[idx] = lv;
        } else { // MODE 2
            int b = r >> 11, s = r & 2047;
            int h = c0 >> 6, d = c0 & 63;
            size_t idx = ((size_t)(b * PH + h) * PS + s) * PD + d;
            float4 av = *(const float4*)&attn[idx];
            float4 o;
            o.x = (av.x * ascv + abiv) * (1.f + v0 * gain);
            o.y = (av.y * ascv + abiv) * (1.f + v1 * gain);
            o.z = (av.z * ascv + abiv) * (1.f + v2 * gain);
            o.w = (av.w * ascv + abiv) * (1.f + v3 * gain);
            *(float4*)&C[(size_t)r * N + c0] = o;
        }
    }
}

// ---------------------------------------------------------------------------
// MFMA flash attention v2: cooperative double-buffered LDS staging.
// Block = 4 waves x 32 q-rows = 128 q rows. Per 64-seq tile the block
// stages khi/klo/vthi/vtlo (32 KB) into XOR-swizzled LDS; each wave
// computes S^T = K.Q^T (6 MFMA, split-bf16) for its 2 q-subtiles, does
// the online softmax in-lane, and PV as O^T = V^T.P^T (3 MFMA) with the
// sequence-permuted V^T so P^T fragments come straight from registers.
// Reg-staged async split: global loads for tile t+1 issue before the
// compute of tile t; ds_writes after. One barrier per tile.
// ---------------------------------------------------------------------------
__global__ __launch_bounds__(256, 2)
void flash_mfma(const float* qf,
                const unsigned short* __restrict__ khi,
                const unsigned short* __restrict__ klo,
                const unsigned short* __restrict__ vthi,
                const unsigned short* __restrict__ vtlo,
                float* attn)
{
    __shared__ int4 ldsv[4096];                    // 64 KB: 2 bufs x 4 planes x 8KB
    char* const ldsb = (char*)ldsv;

    const int tid  = threadIdx.x;
    const int lane = tid & 63;
    const int w    = tid >> 6;
    const int bh   = blockIdx.z * PH + blockIdx.y;
    const int lq   = lane & 15;
    const int lg   = lane >> 4;
    const int q0   = blockIdx.x * 128 + w * 32;

    const size_t kbase = (size_t)bh * PS * PD;   // K rows   [S][D]
    const size_t vbase = (size_t)bh * PD * PS;   // V^T rows [D][S] (permuted)

    const unsigned short* const gsrc[4] = {khi + kbase, klo + kbase,
                                           vthi + vbase, vtlo + vbase};

    // ---- Q fragments (scale 1/8 folded in), 2 q-subtiles per wave
    short8 qh[2][2], ql[2][2];
    #pragma unroll
    for (int u = 0; u < 2; ++u) {
        const float* qp = qf + ((size_t)bh * PS + q0 + 16 * u + lq) * PD + 8 * lg;
        #pragma unroll
        for (int t = 0; t < 2; ++t)
            #pragma unroll
            for (int b = 0; b < 8; ++b) {
                float x = qp[t * 32 + b] * 0.125f;
                unsigned short h, l;
                split2(x, h, l);
                qh[u][t][b] = (short)h;
                ql[u][t][b] = (short)l;
            }
    }

    f32x4 ot[2][4];
    #pragma unroll
    for (int u = 0; u < 2; ++u)
        #pragma unroll
        for (int mt = 0; mt < 4; ++mt)
            ot[u][mt] = (f32x4){0.f, 0.f, 0.f, 0.f};
    float m_run[2] = {-3.0e38f, -3.0e38f};
    float l_run[2] = {0.f, 0.f};

    // staging: chunk c = tid + 256r; plane = r>>1 effectively; cc = c & 511
    int4 stg[8];
    const int colB = (tid & 7) * 16;              // byte col within 128B row

    auto LOADREGS = [&](int kt) {
        #pragma unroll
        for (int r = 0; r < 8; ++r) {
            const int plane = r >> 1;             // 0:khi 1:klo 2:vthi 3:vtlo
            const int row   = ((tid + 256 * (r & 1)) & 511) >> 3;  // 0..63
            size_t off = (plane < 2)
                       ? (size_t)(kt + row) * PD + (colB >> 1)
                       : (size_t)row * PS + kt + (colB >> 1);
            stg[r] = *(const int4*)(gsrc[plane] + off);
        }
    };
    auto DSWRITE = [&](int buf) {
        #pragma unroll
        for (int r = 0; r < 8; ++r) {
            const int plane = r >> 1;
            const int row   = ((tid + 256 * (r & 1)) & 511) >> 3;
            int off = buf * 32768 + plane * 8192 + row * 128
                    + (colB ^ ((row & 7) << 4));
            *(int4*)(ldsb + off) = stg[r];
        }
    };

    LOADREGS(0);
    DSWRITE(0);
    __syncthreads();

    int buf = 0;
    for (int kti = 0; kti < PS / 64; ++kti) {
        const bool pf = (kti + 1 < PS / 64);
        if (pf) LOADREGS((kti + 1) * 64);

        const char* const L = ldsb + buf * 32768;

        // ---- S^T tiles for both q-subtiles
        f32x4 st[2][4];
        #pragma unroll
        for (int mt = 0; mt < 4; ++mt) {
            const int row = 16 * mt + lq;
            const int swz = (row & 7) << 4;
            const char* kr = L + row * 128;
            short8 ah0 = *(const short8*)(kr + ((16 * lg) ^ swz));
            short8 ah1 = *(const short8*)(kr + ((64 + 16 * lg) ^ swz));
            short8 al0 = *(const short8*)(kr + 8192 + ((16 * lg) ^ swz));
            short8 al1 = *(const short8*)(kr + 8192 + ((64 + 16 * lg) ^ swz));
            #pragma unroll
            for (int u = 0; u < 2; ++u) {
                f32x4 acc = {0.f, 0.f, 0.f, 0.f};
                acc = MFMA16(ah0, qh[u][0], acc, 0, 0, 0);
                acc = MFMA16(ah1, qh[u][1], acc, 0, 0, 0);
                acc = MFMA16(ah0, ql[u][0], acc, 0, 0, 0);
                acc = MFMA16(ah1, ql[u][1], acc, 0, 0, 0);
                acc = MFMA16(al0, qh[u][0], acc, 0, 0, 0);
                acc = MFMA16(al1, qh[u][1], acc, 0, 0, 0);
                st[u][mt] = acc;
            }
        }

        // ---- online softmax + P pack, per q-subtile
        short8 pbh[2][2], pbl[2][2];
        #pragma unroll
        for (int u = 0; u < 2; ++u) {
            float pmax = -3.0e38f;
            #pragma unroll
            for (int mt = 0; mt < 4; ++mt)
                #pragma unroll
                for (int j = 0; j < 4; ++j)
                    pmax = fmaxf(pmax, st[u][mt][j]);
            pmax = fmaxf(pmax, __shfl_xor(pmax, 16));
            pmax = fmaxf(pmax, __shfl_xor(pmax, 32));
            float mnew = fmaxf(m_run[u], pmax);
            float corr = __expf(m_run[u] - mnew);
            float psum = 0.f;
            #pragma unroll
            for (int mt = 0; mt < 4; ++mt)
                #pragma unroll
                for (int j = 0; j < 4; ++j) {
                    float p = __expf(st[u][mt][j] - mnew);
                    psum += p;
                    st[u][mt][j] = p;
                }
            psum += __shfl_xor(psum, 16);
            psum += __shfl_xor(psum, 32);
            l_run[u] = l_run[u] * corr + psum;
            m_run[u] = mnew;
            #pragma unroll
            for (int mt = 0; mt < 4; ++mt)
                #pragma unroll
                for (int j = 0; j < 4; ++j)
                    ot[u][mt][j] *= corr;
            #pragma unroll
            for (int b = 0; b < 8; ++b) {
                const int mt0 = (b >> 2) << 1;
                unsigned short h0, l0, h1, l1;
                split2(st[u][mt0][b & 3], h0, l0);
                split2(st[u][mt0 + 1][b & 3], h1, l1);
                pbh[u][0][b] = (short)h0; pbl[u][0][b] = (short)l0;
                pbh[u][1][b] = (short)h1; pbl[u][1][b] = (short)l1;
            }
        }

        // ---- O^T += V^T . P^T
        #pragma unroll
        for (int t = 0; t < 2; ++t) {
            #pragma unroll
            for (int mt = 0; mt < 4; ++mt) {
                const int row = 16 * mt + lq;
                const int swz = (row & 7) << 4;
                const char* vr = L + 16384 + row * 128;
                short8 vh = *(const short8*)(vr + ((t * 64 + 16 * lg) ^ swz));
                short8 vl = *(const short8*)(vr + 8192 + ((t * 64 + 16 * lg) ^ swz));
                #pragma unroll
                for (int u = 0; u < 2; ++u) {
                    ot[u][mt] = MFMA16(vh, pbh[u][t], ot[u][mt], 0, 0, 0);
                    ot[u][mt] = MFMA16(vh, pbl[u][t], ot[u][mt], 0, 0, 0);
                    ot[u][mt] = MFMA16(vl, pbh[u][t], ot[u][mt], 0, 0, 0);
                }
            }
        }

        if (pf) DSWRITE(buf ^ 1);
        __syncthreads();
        buf ^= 1;
    }

    // ---- epilogue: attn[bh][q0+16u+lq][d], d = 16*mt + 4*lg + j
    #pragma unroll
    for (int u = 0; u < 2; ++u) {
        const float inv = 1.f / l_run[u];
        float* op = attn + ((size_t)bh * PS + q0 + 16 * u + lq) * PD + 4 * lg;
        #pragma unroll
        for (int mt = 0; mt < 4; ++mt) {
            float4 o;
            o.x = ot[u][mt][0] * inv; o.y = ot[u][mt][1] * inv;
            o.z = ot[u][mt][2] * inv; o.w = ot[u][mt][3] * inv;
            *(float4*)(op + 16 * mt) = o;
        }
    }
}

// ---------------------------------------------------------------------------
extern "C" void kernel_launch(void* const* d_in, const int* in_sizes, int n_in,
                              void* d_out, int out_size, void* d_ws, size_t ws_size,
                              hipStream_t stream)
{
    const float* query = (const float*)d_in[0];
    const float* Wq  = (const float*)d_in[1];  const float* bq  = (const float*)d_in[2];
    const float* Wk  = (const float*)d_in[3];  const float* bk  = (const float*)d_in[4];
    const float* Wv  = (const float*)d_in[5];  const float* bv  = (const float*)d_in[6];
    const float* Wo  = (const float*)d_in[7];  const float* bo  = (const float*)d_in[8];
    const float* Wm1 = (const float*)d_in[9];  const float* bm1 = (const float*)d_in[10];
    const float* Wm2 = (const float*)d_in[11]; const float* bm2 = (const float*)d_in[12];
    const float* dop = (const float*)d_in[13];
    const float* ser = (const float*)d_in[14];
    const float* nor = (const float*)d_in[15];
    const float* ach = (const float*)d_in[16];
    const float* asc = (const float*)d_in[17];
    const float* abi = (const float*)d_in[18];
    float* out = (float*)d_out;

    // Workspace (104 MB):
    //  [  0MB, 32MB)  qf32 [B,H,S,D]   -> attn overwrites it in flash_mfma
    //  [ 32MB, 64MB)  khi,klo bf16 planes -> attnf fp32 overlays after attn
    //  [ 64MB, 96MB)  vthi,vtlo bf16 planes (V^T: [B,H,D,S], seq-permuted)
    //  [ 96MB,104MB)  h1 fp32 [M,256]
    float* ws = (float*)d_ws;
    float*          qf32  = ws;                                   // 8388608 f
    unsigned short* khi   = (unsigned short*)(ws + 8388608);      // 8388608 us
    unsigned short* klo   = khi + 8388608;
    unsigned short* vthi  = (unsigned short*)(ws + 16777216);
    unsigned short* vtlo  = vthi + 8388608;
    float*          h1    = ws + 25165824;                        // 2097152 f
    float*          attnf = ws + 8388608;                         // over k planes

    dim3 blk(256);

    // Projections
    gemm_nt<1, false><<<dim3(PM / TM, PE / TN), blk, 0, stream>>>(
        query, Wq, bq, qf32, nullptr, nullptr, PM, PE, PE,
        nullptr, nullptr, nullptr, nullptr, nullptr, nullptr, nullptr);
    gemm_nt<3, false><<<dim3(PM / TM, PE / TN), blk, 0, stream>>>(
        query, Wk, bk, nullptr, khi, klo, PM, PE, PE,
        nullptr, nullptr, nullptr, nullptr, nullptr, nullptr, nullptr);
    gemm_nt<4, false><<<dim3(PM / TM, PE / TN), blk, 0, stream>>>(
        query, Wv, bv, nullptr, vthi, vtlo, PM, PE, PE,
        nullptr, nullptr, nullptr, nullptr, nullptr, nullptr, nullptr);

    // MLP layer 1 (fp32): h1 = relu(query @ Wm1^T + bm1)
    gemm_nt<0, true><<<dim3(PM / TM, 256 / TN), blk, 0, stream>>>(
        query, Wm1, bm1, h1, nullptr, nullptr, PM, 256, PE,
        nullptr, nullptr, nullptr, nullptr, nullptr, nullptr, nullptr);

    // Flash attention (attn -> over qf32); 128 q rows per block
    flash_mfma<<<dim3(PS / 128, PH, PB), blk, 0, stream>>>(
        qf32, khi, klo, vthi, vtlo, qf32);

    // MLP layer 2 + neuromod combine: attnf (over k planes)
    gemm_nt<2, false><<<dim3(PM / TM, PE / TN), blk, 0, stream>>>(
        h1, Wm2, bm2, attnf, nullptr, nullptr, PM, PE, 256,
        qf32, dop, ser, nor, ach, asc, abi);

    // Output projection
    gemm_nt<0, false><<<dim3(PM / TM, PE / TN), blk, 0, stream>>>(
        attnf, Wo, bo, out, nullptr, nullptr, PM, PE, PE,
        nullptr, nullptr, nullptr, nullptr, nullptr, nullptr, nullptr);
}

// Round 5
// 782.884 us; speedup vs baseline: 3.4474x; 1.9787x over previous
//
#include <hip/hip_runtime.h>
#include <hip/hip_bf16.h>
#include <cstdint>

// Problem constants
#define PB 4
#define PS 2048
#define PE 1024
#define PH 16
#define PD 64
#define PM (PB * PS)      // 8192 rows

typedef __attribute__((ext_vector_type(8))) short short8;   // 8 bf16 (4 VGPR)
typedef __attribute__((ext_vector_type(4))) float f32x4;

#define MFMA16 __builtin_amdgcn_mfma_f32_16x16x32_bf16

// fp32 -> bf16 round-to-nearest-even (finite inputs)
__device__ inline unsigned short bf16rn(float x) {
    unsigned u = __builtin_bit_cast(unsigned, x);
    u += 0x7FFFu + ((u >> 16) & 1u);
    return (unsigned short)(u >> 16);
}
__device__ inline float bf16tof(unsigned short h) {
    unsigned u = ((unsigned)h) << 16;
    return __builtin_bit_cast(float, u);
}
__device__ inline void split2(float x, unsigned short& h, unsigned short& l) {
    h = bf16rn(x);
    l = bf16rn(x - bf16tof(h));
}

// ---------------------------------------------------------------------------
// Split-bf16 MFMA NT GEMM: C = A(MxK,row) . Bw(NxK,row)^T + bias.
// A,B read as fp32, split in-register to bf16 hi/lo planes in LDS
// (same global bytes as bf16 planes; compensated product AhBh+AhBl+AlBh
// gives ~2^-17 relative error, fp32-equivalent for this problem).
// Geometry: 128x128 tile, BK=64, 4 waves (2x2) of 64x64 each,
// 16x16x32 MFMA, lane(lq,lg) owns C[16mt+4lg+j][16nt+lq] per subtile.
// LDS: 4 planes (Ahi,Alo,Bhi,Blo) of [128 rows][128 B], XOR-swizzled
// byte ^= (row&7)<<4 (proven conflict-free pattern from flash).
// MODE 0: C[m*N+n] fp32               (optional RELU)
// MODE 1: fp32 at BHSD-permuted index (Q projection)
// MODE 2: neuromod combine epilogue -> fp32 C
// MODE 3: bf16 hi/lo planes at BHSD index      (K projection)
// MODE 4: bf16 hi/lo planes at BHDS (V^T) index with PV seq permutation
// ---------------------------------------------------------------------------
template<int MODE, bool RELU>
__global__ __launch_bounds__(256, 2)
void gemm_nt(const float* __restrict__ A, const float* __restrict__ Bw,
             const float* __restrict__ bias, float* __restrict__ C,
             unsigned short* __restrict__ Ohi, unsigned short* __restrict__ Olo,
             int M, int N, int K,
             const float* __restrict__ attn,
             const float* __restrict__ g0, const float* __restrict__ g1,
             const float* __restrict__ g2, const float* __restrict__ g3,
             const float* __restrict__ asc, const float* __restrict__ abi)
{
    __shared__ int4 ldsq[4096];                 // 64 KB = 4 planes x 16 KB
    char* const lds = (char*)ldsq;

    const int tid  = threadIdx.x;
    const int lane = tid & 63;
    const int w    = tid >> 6;
    const int lq   = lane & 15;
    const int lg   = lane >> 4;
    const int wm   = (w >> 1) * 64;             // wave row offset in tile
    const int wn   = (w & 1) * 64;              // wave col offset in tile
    const int m0   = blockIdx.x * 128;
    const int n0   = blockIdx.y * 128;

    const int irow = tid >> 3;                  // 0..31 (+32r)
    const int ic8  = (tid & 7) * 8;             // k element offset (8 floats)
    const int woff = (ic8 * 2);                 // byte col within 128B row

    f32x4 acc[4][4];
    #pragma unroll
    for (int mt = 0; mt < 4; ++mt)
        #pragma unroll
        for (int nt = 0; nt < 4; ++nt)
            acc[mt][nt] = (f32x4){0.f, 0.f, 0.f, 0.f};

    for (int k0 = 0; k0 < K; k0 += 64) {
        // ---- stage: fp32 -> split -> swizzled LDS planes
        #pragma unroll
        for (int mat = 0; mat < 2; ++mat) {
            const float* const src = mat ? Bw : A;
            const int rbase = mat ? n0 : m0;
            const int pbase = mat ? 32768 : 0;
            #pragma unroll
            for (int r = 0; r < 4; ++r) {
                const int row = irow + 32 * r;
                const float* p = src + (size_t)(rbase + row) * K + k0 + ic8;
                float4 f0 = *(const float4*)p;
                float4 f1 = *(const float4*)(p + 4);
                short8 vh, vl;
                {
                    unsigned short h, l;
                    split2(f0.x, h, l); vh[0] = (short)h; vl[0] = (short)l;
                    split2(f0.y, h, l); vh[1] = (short)h; vl[1] = (short)l;
                    split2(f0.z, h, l); vh[2] = (short)h; vl[2] = (short)l;
                    split2(f0.w, h, l); vh[3] = (short)h; vl[3] = (short)l;
                    split2(f1.x, h, l); vh[4] = (short)h; vl[4] = (short)l;
                    split2(f1.y, h, l); vh[5] = (short)h; vl[5] = (short)l;
                    split2(f1.z, h, l); vh[6] = (short)h; vl[6] = (short)l;
                    split2(f1.w, h, l); vh[7] = (short)h; vl[7] = (short)l;
                }
                const int off = row * 128 + (woff ^ ((row & 7) << 4));
                *(short8*)(lds + pbase + off)         = vh;
                *(short8*)(lds + pbase + 16384 + off) = vl;
            }
        }
        __syncthreads();

        // ---- compute: 96 MFMA per wave (3-term compensated)
        #pragma unroll
        for (int kh = 0; kh < 2; ++kh) {
            short8 afh[4], afl[4];
            #pragma unroll
            for (int mt = 0; mt < 4; ++mt) {
                const int row = wm + 16 * mt + lq;
                const int off = row * 128 + ((kh * 64 + 16 * lg) ^ ((row & 7) << 4));
                afh[mt] = *(const short8*)(lds + off);
                afl[mt] = *(const short8*)(lds + 16384 + off);
            }
            #pragma unroll
            for (int nt = 0; nt < 4; ++nt) {
                const int row = wn + 16 * nt + lq;
                const int off = row * 128 + ((kh * 64 + 16 * lg) ^ ((row & 7) << 4));
                short8 bfh = *(const short8*)(lds + 32768 + off);
                short8 bfl = *(const short8*)(lds + 49152 + off);
                #pragma unroll
                for (int mt = 0; mt < 4; ++mt) {
                    acc[mt][nt] = MFMA16(afh[mt], bfh, acc[mt][nt], 0, 0, 0);
                    acc[mt][nt] = MFMA16(afh[mt], bfl, acc[mt][nt], 0, 0, 0);
                    acc[mt][nt] = MFMA16(afl[mt], bfh, acc[mt][nt], 0, 0, 0);
                }
            }
        }
        __syncthreads();
    }

    // ---- epilogue (MFMA C layout: m = 16mt+4lg+j, n = 16nt+lq per subtile)
    float gain = 0.f, ascv = 0.f, abiv = 0.f;
    if (MODE == 2) {
        gain = 0.25f * (*g0 + *g1 + *g2 + *g3);
        ascv = *asc;
        abiv = *abi;
    }

    #pragma unroll
    for (int nt = 0; nt < 4; ++nt) {
        const int n  = n0 + wn + 16 * nt + lq;
        const float bv = bias[n];
        #pragma unroll
        for (int mt = 0; mt < 4; ++mt) {
            #pragma unroll
            for (int j = 0; j < 4; ++j) {
                const int m = m0 + wm + 16 * mt + 4 * lg + j;
                float v = acc[mt][nt][j] + bv;
                if (RELU) v = fmaxf(v, 0.f);
                if (MODE == 0) {
                    C[(size_t)m * N + n] = v;
                } else if (MODE == 1) {
                    const int b = m >> 11, s = m & 2047;
                    const int h = n >> 6, d = n & 63;
                    C[((size_t)(b * PH + h) * PS + s) * PD + d] = v;
                } else if (MODE == 3) {
                    const int b = m >> 11, s = m & 2047;
                    const int h = n >> 6, d = n & 63;
                    const size_t idx = ((size_t)(b * PH + h) * PS + s) * PD + d;
                    unsigned short hh, ll;
                    split2(v, hh, ll);
                    Ohi[idx] = hh; Olo[idx] = ll;
                } else if (MODE == 4) {
                    // s = m with in-tile PV permutation on the seq index
                    const int b = m >> 11;
                    const int h = n >> 6, d = n & 63;
                    const int scol = (m & 2047 & ~63) + ((mt & 1) << 5)
                                   + (lg << 3) + ((mt >> 1) << 2) + j;
                    const size_t idx = ((size_t)(b * PH + h) * PD + d) * PS + scol;
                    unsigned short hh, ll;
                    split2(v, hh, ll);
                    Ohi[idx] = hh; Olo[idx] = ll;
                } else { // MODE 2
                    const int b = m >> 11, s = m & 2047;
                    const int h = n >> 6, d = n & 63;
                    const float av = attn[((size_t)(b * PH + h) * PS + s) * PD + d];
                    C[(size_t)m * N + n] = (av * ascv + abiv) * (1.f + v * gain);
                }
            }
        }
    }
}

// ---------------------------------------------------------------------------
// MFMA flash attention v2 (unchanged from round 4 — passes at ~400us).
// ---------------------------------------------------------------------------
__global__ __launch_bounds__(256, 2)
void flash_mfma(const float* qf,
                const unsigned short* __restrict__ khi,
                const unsigned short* __restrict__ klo,
                const unsigned short* __restrict__ vthi,
                const unsigned short* __restrict__ vtlo,
                float* attn)
{
    __shared__ int4 ldsv[4096];                    // 64 KB: 2 bufs x 4 planes x 8KB
    char* const ldsb = (char*)ldsv;

    const int tid  = threadIdx.x;
    const int lane = tid & 63;
    const int w    = tid >> 6;
    const int bh   = blockIdx.z * PH + blockIdx.y;
    const int lq   = lane & 15;
    const int lg   = lane >> 4;
    const int q0   = blockIdx.x * 128 + w * 32;

    const size_t kbase = (size_t)bh * PS * PD;   // K rows   [S][D]
    const size_t vbase = (size_t)bh * PD * PS;   // V^T rows [D][S] (permuted)

    const unsigned short* const gsrc[4] = {khi + kbase, klo + kbase,
                                           vthi + vbase, vtlo + vbase};

    // ---- Q fragments (scale 1/8 folded in), 2 q-subtiles per wave
    short8 qh[2][2], ql[2][2];
    #pragma unroll
    for (int u = 0; u < 2; ++u) {
        const float* qp = qf + ((size_t)bh * PS + q0 + 16 * u + lq) * PD + 8 * lg;
        #pragma unroll
        for (int t = 0; t < 2; ++t)
            #pragma unroll
            for (int b = 0; b < 8; ++b) {
                float x = qp[t * 32 + b] * 0.125f;
                unsigned short h, l;
                split2(x, h, l);
                qh[u][t][b] = (short)h;
                ql[u][t][b] = (short)l;
            }
    }

    f32x4 ot[2][4];
    #pragma unroll
    for (int u = 0; u < 2; ++u)
        #pragma unroll
        for (int mt = 0; mt < 4; ++mt)
            ot[u][mt] = (f32x4){0.f, 0.f, 0.f, 0.f};
    float m_run[2] = {-3.0e38f, -3.0e38f};
    float l_run[2] = {0.f, 0.f};

    int4 stg[8];
    const int colB = (tid & 7) * 16;              // byte col within 128B row

    auto LOADREGS = [&](int kt) {
        #pragma unroll
        for (int r = 0; r < 8; ++r) {
            const int plane = r >> 1;             // 0:khi 1:klo 2:vthi 3:vtlo
            const int row   = ((tid + 256 * (r & 1)) & 511) >> 3;  // 0..63
            size_t off = (plane < 2)
                       ? (size_t)(kt + row) * PD + (colB >> 1)
                       : (size_t)row * PS + kt + (colB >> 1);
            stg[r] = *(const int4*)(gsrc[plane] + off);
        }
    };
    auto DSWRITE = [&](int buf) {
        #pragma unroll
        for (int r = 0; r < 8; ++r) {
            const int plane = r >> 1;
            const int row   = ((tid + 256 * (r & 1)) & 511) >> 3;
            int off = buf * 32768 + plane * 8192 + row * 128
                    + (colB ^ ((row & 7) << 4));
            *(int4*)(ldsb + off) = stg[r];
        }
    };

    LOADREGS(0);
    DSWRITE(0);
    __syncthreads();

    int buf = 0;
    for (int kti = 0; kti < PS / 64; ++kti) {
        const bool pf = (kti + 1 < PS / 64);
        if (pf) LOADREGS((kti + 1) * 64);

        const char* const L = ldsb + buf * 32768;

        // ---- S^T tiles for both q-subtiles
        f32x4 st[2][4];
        #pragma unroll
        for (int mt = 0; mt < 4; ++mt) {
            const int row = 16 * mt + lq;
            const int swz = (row & 7) << 4;
            const char* kr = L + row * 128;
            short8 ah0 = *(const short8*)(kr + ((16 * lg) ^ swz));
            short8 ah1 = *(const short8*)(kr + ((64 + 16 * lg) ^ swz));
            short8 al0 = *(const short8*)(kr + 8192 + ((16 * lg) ^ swz));
            short8 al1 = *(const short8*)(kr + 8192 + ((64 + 16 * lg) ^ swz));
            #pragma unroll
            for (int u = 0; u < 2; ++u) {
                f32x4 acc = {0.f, 0.f, 0.f, 0.f};
                acc = MFMA16(ah0, qh[u][0], acc, 0, 0, 0);
                acc = MFMA16(ah1, qh[u][1], acc, 0, 0, 0);
                acc = MFMA16(ah0, ql[u][0], acc, 0, 0, 0);
                acc = MFMA16(ah1, ql[u][1], acc, 0, 0, 0);
                acc = MFMA16(al0, qh[u][0], acc, 0, 0, 0);
                acc = MFMA16(al1, qh[u][1], acc, 0, 0, 0);
                st[u][mt] = acc;
            }
        }

        // ---- online softmax + P pack, per q-subtile
        short8 pbh[2][2], pbl[2][2];
        #pragma unroll
        for (int u = 0; u < 2; ++u) {
            float pmax = -3.0e38f;
            #pragma unroll
            for (int mt = 0; mt < 4; ++mt)
                #pragma unroll
                for (int j = 0; j < 4; ++j)
                    pmax = fmaxf(pmax, st[u][mt][j]);
            pmax = fmaxf(pmax, __shfl_xor(pmax, 16));
            pmax = fmaxf(pmax, __shfl_xor(pmax, 32));
            float mnew = fmaxf(m_run[u], pmax);
            float corr = __expf(m_run[u] - mnew);
            float psum = 0.f;
            #pragma unroll
            for (int mt = 0; mt < 4; ++mt)
                #pragma unroll
                for (int j = 0; j < 4; ++j) {
                    float p = __expf(st[u][mt][j] - mnew);
                    psum += p;
                    st[u][mt][j] = p;
                }
            psum += __shfl_xor(psum, 16);
            psum += __shfl_xor(psum, 32);
            l_run[u] = l_run[u] * corr + psum;
            m_run[u] = mnew;
            #pragma unroll
            for (int mt = 0; mt < 4; ++mt)
                #pragma unroll
                for (int j = 0; j < 4; ++j)
                    ot[u][mt][j] *= corr;
            #pragma unroll
            for (int b = 0; b < 8; ++b) {
                const int mt0 = (b >> 2) << 1;
                unsigned short h0, l0, h1, l1;
                split2(st[u][mt0][b & 3], h0, l0);
                split2(st[u][mt0 + 1][b & 3], h1, l1);
                pbh[u][0][b] = (short)h0; pbl[u][0][b] = (short)l0;
                pbh[u][1][b] = (short)h1; pbl[u][1][b] = (short)l1;
            }
        }

        // ---- O^T += V^T . P^T
        #pragma unroll
        for (int t = 0; t < 2; ++t) {
            #pragma unroll
            for (int mt = 0; mt < 4; ++mt) {
                const int row = 16 * mt + lq;
                const int swz = (row & 7) << 4;
                const char* vr = L + 16384 + row * 128;
                short8 vh = *(const short8*)(vr + ((t * 64 + 16 * lg) ^ swz));
                short8 vl = *(const short8*)(vr + 8192 + ((t * 64 + 16 * lg) ^ swz));
                #pragma unroll
                for (int u = 0; u < 2; ++u) {
                    ot[u][mt] = MFMA16(vh, pbh[u][t], ot[u][mt], 0, 0, 0);
                    ot[u][mt] = MFMA16(vh, pbl[u][t], ot[u][mt], 0, 0, 0);
                    ot[u][mt] = MFMA16(vl, pbh[u][t], ot[u][mt], 0, 0, 0);
                }
            }
        }

        if (pf) DSWRITE(buf ^ 1);
        __syncthreads();
        buf ^= 1;
    }

    // ---- epilogue: attn[bh][q0+16u+lq][d], d = 16*mt + 4*lg + j
    #pragma unroll
    for (int u = 0; u < 2; ++u) {
        const float inv = 1.f / l_run[u];
        float* op = attn + ((size_t)bh * PS + q0 + 16 * u + lq) * PD + 4 * lg;
        #pragma unroll
        for (int mt = 0; mt < 4; ++mt) {
            float4 o;
            o.x = ot[u][mt][0] * inv; o.y = ot[u][mt][1] * inv;
            o.z = ot[u][mt][2] * inv; o.w = ot[u][mt][3] * inv;
            *(float4*)(op + 16 * mt) = o;
        }
    }
}

// ---------------------------------------------------------------------------
extern "C" void kernel_launch(void* const* d_in, const int* in_sizes, int n_in,
                              void* d_out, int out_size, void* d_ws, size_t ws_size,
                              hipStream_t stream)
{
    const float* query = (const float*)d_in[0];
    const float* Wq  = (const float*)d_in[1];  const float* bq  = (const float*)d_in[2];
    const float* Wk  = (const float*)d_in[3];  const float* bk  = (const float*)d_in[4];
    const float* Wv  = (const float*)d_in[5];  const float* bv  = (const float*)d_in[6];
    const float* Wo  = (const float*)d_in[7];  const float* bo  = (const float*)d_in[8];
    const float* Wm1 = (const float*)d_in[9];  const float* bm1 = (const float*)d_in[10];
    const float* Wm2 = (const float*)d_in[11]; const float* bm2 = (const float*)d_in[12];
    const float* dop = (const float*)d_in[13];
    const float* ser = (const float*)d_in[14];
    const float* nor = (const float*)d_in[15];
    const float* ach = (const float*)d_in[16];
    const float* asc = (const float*)d_in[17];
    const float* abi = (const float*)d_in[18];
    float* out = (float*)d_out;

    // Workspace (104 MB):
    //  [  0MB, 32MB)  qf32 [B,H,S,D]   -> attn overwrites it in flash_mfma
    //  [ 32MB, 64MB)  khi,klo bf16 planes -> attnf fp32 overlays after attn
    //  [ 64MB, 96MB)  vthi,vtlo bf16 planes (V^T: [B,H,D,S], seq-permuted)
    //  [ 96MB,104MB)  h1 fp32 [M,256]
    float* ws = (float*)d_ws;
    float*          qf32  = ws;                                   // 8388608 f
    unsigned short* khi   = (unsigned short*)(ws + 8388608);      // 8388608 us
    unsigned short* klo   = khi + 8388608;
    unsigned short* vthi  = (unsigned short*)(ws + 16777216);
    unsigned short* vtlo  = vthi + 8388608;
    float*          h1    = ws + 25165824;                        // 2097152 f
    float*          attnf = ws + 8388608;                         // over k planes

    dim3 blk(256);

    // Projections (MFMA engine, 128x128 tiles)
    gemm_nt<1, false><<<dim3(PM / 128, PE / 128), blk, 0, stream>>>(
        query, Wq, bq, qf32, nullptr, nullptr, PM, PE, PE,
        nullptr, nullptr, nullptr, nullptr, nullptr, nullptr, nullptr);
    gemm_nt<3, false><<<dim3(PM / 128, PE / 128), blk, 0, stream>>>(
        query, Wk, bk, nullptr, khi, klo, PM, PE, PE,
        nullptr, nullptr, nullptr, nullptr, nullptr, nullptr, nullptr);
    gemm_nt<4, false><<<dim3(PM / 128, PE / 128), blk, 0, stream>>>(
        query, Wv, bv, nullptr, vthi, vtlo, PM, PE, PE,
        nullptr, nullptr, nullptr, nullptr, nullptr, nullptr, nullptr);

    // MLP layer 1: h1 = relu(query @ Wm1^T + bm1)  [8192,256], K=1024
    gemm_nt<0, true><<<dim3(PM / 128, 256 / 128), blk, 0, stream>>>(
        query, Wm1, bm1, h1, nullptr, nullptr, PM, 256, PE,
        nullptr, nullptr, nullptr, nullptr, nullptr, nullptr, nullptr);

    // Flash attention (attn -> over qf32); 128 q rows per block
    flash_mfma<<<dim3(PS / 128, PH, PB), blk, 0, stream>>>(
        qf32, khi, klo, vthi, vtlo, qf32);

    // MLP layer 2 + neuromod combine: attnf (over k planes), K=256
    gemm_nt<2, false><<<dim3(PM / 128, PE / 128), blk, 0, stream>>>(
        h1, Wm2, bm2, attnf, nullptr, nullptr, PM, PE, 256,
        qf32, dop, ser, nor, ach, asc, abi);

    // Output projection: out = attnf @ Wo^T + bo
    gemm_nt<0, false><<<dim3(PM / 128, PE / 128), blk, 0, stream>>>(
        attnf, Wo, bo, out, nullptr, nullptr, PM, PE, PE,
        nullptr, nullptr, nullptr, nullptr, nullptr, nullptr, nullptr);
}

// Round 6
// 489.492 us; speedup vs baseline: 5.5137x; 1.5994x over previous
//
#include <hip/hip_runtime.h>
#include <hip/hip_bf16.h>
#include <cstdint>

// Problem constants
#define PB 4
#define PS 2048
#define PE 1024
#define PH 16
#define PD 64
#define PM (PB * PS)      // 8192 rows

typedef __attribute__((ext_vector_type(8))) short short8;   // 8 bf16 (4 VGPR)
typedef __attribute__((ext_vector_type(4))) float f32x4;

#define MFMA16 __builtin_amdgcn_mfma_f32_16x16x32_bf16

#define GLOAD_LDS(gp, lp) __builtin_amdgcn_global_load_lds(                    \
    (const __attribute__((address_space(1))) void*)(gp),                       \
    (__attribute__((address_space(3))) void*)(lp), 16, 0, 0)

// fp32 -> bf16 round-to-nearest-even (finite inputs)
__device__ inline unsigned short bf16rn(float x) {
    unsigned u = __builtin_bit_cast(unsigned, x);
    u += 0x7FFFu + ((u >> 16) & 1u);
    return (unsigned short)(u >> 16);
}
__device__ inline float bf16tof(unsigned short h) {
    unsigned u = ((unsigned)h) << 16;
    return __builtin_bit_cast(float, u);
}
__device__ inline void split2(float x, unsigned short& h, unsigned short& l) {
    h = bf16rn(x);
    l = bf16rn(x - bf16tof(h));
}

// ---------------------------------------------------------------------------
// split_mat: fp32 matrix -> bf16 hi/lo planes (row-major, same shape)
// ---------------------------------------------------------------------------
__global__ __launch_bounds__(256)
void split_mat(const float* __restrict__ src, unsigned short* __restrict__ hi,
               unsigned short* __restrict__ lo, int n4)
{
    int i = blockIdx.x * 256 + threadIdx.x;
    if (i >= n4) return;
    float4 f = ((const float4*)src)[i];
    ushort4 h, l;
    split2(f.x, h.x, l.x); split2(f.y, h.y, l.y);
    split2(f.z, h.z, l.z); split2(f.w, h.w, l.w);
    ((ushort4*)hi)[i] = h;
    ((ushort4*)lo)[i] = l;
}

// ---------------------------------------------------------------------------
// Plane-fed split-bf16 MFMA NT GEMM (presplit path):
// A,B given as bf16 hi/lo planes [rows][K]; staged via global_load_lds with
// pre-swizzled per-lane source (LDS layout = [128 rows][128B], byte col
// XOR (row&7)<<4). Compensated product AhBh+AhBl+AlBh.
// 128x128 tile, BK=64, 4 waves (2x2) of 64x64, 16x16x32 MFMA;
// lane(lq,lg) owns C[16mt+4lg+j][16nt+lq] per 16x16 subtile.
// MODE 0: fp32 C[m*N+n]            (optional RELU)
// MODE 1: fp32 at BHSD index       (Q projection)
// MODE 3: bf16 hi/lo planes at BHSD index      (K projection)
// MODE 4: bf16 hi/lo planes at BHDS (V^T) index + PV seq permutation
// MODE 5: bf16 hi/lo planes row-major [M][N]   (h1, with RELU)
// MODE 6: neuromod combine -> bf16 hi/lo planes [M][N] (attnf)
// ---------------------------------------------------------------------------
template<int MODE, bool RELU>
__global__ __launch_bounds__(256, 2)
void gemm_pl(const unsigned short* __restrict__ Ahi,
             const unsigned short* __restrict__ Alo,
             const unsigned short* __restrict__ Bhi,
             const unsigned short* __restrict__ Blo,
             const float* __restrict__ bias, float* __restrict__ C,
             unsigned short* __restrict__ Ohi, unsigned short* __restrict__ Olo,
             int M, int N, int K,
             const float* __restrict__ attn,
             const float* __restrict__ g0, const float* __restrict__ g1,
             const float* __restrict__ g2, const float* __restrict__ g3,
             const float* __restrict__ asc, const float* __restrict__ abi)
{
    __shared__ int4 ldsq[4096];                 // 64 KB = 4 planes x 16 KB
    char* const lds = (char*)ldsq;

    const int tid  = threadIdx.x;
    const int lane = tid & 63;
    const int w    = tid >> 6;
    const int lq   = lane & 15;
    const int lg   = lane >> 4;
    const int wm   = (w >> 1) * 64;
    const int wn   = (w & 1) * 64;
    const int m0   = blockIdx.x * 128;
    const int n0   = blockIdx.y * 128;

    // staging source for this wave: 0:Ahi 1:Alo 2:Bhi 3:Blo
    const unsigned short* const gp =
        (w == 0) ? Ahi + (size_t)m0 * K :
        (w == 1) ? Alo + (size_t)m0 * K :
        (w == 2) ? Bhi + (size_t)n0 * K :
                   Blo + (size_t)n0 * K;
    const int ldsbase = w * 16384;
    const int scol8 = (((lane & 7) ^ (lane >> 3)) << 3);   // pre-swizzled col
    const int lrow8 = lane >> 3;

    f32x4 acc[4][4];
    #pragma unroll
    for (int mt = 0; mt < 4; ++mt)
        #pragma unroll
        for (int nt = 0; nt < 4; ++nt)
            acc[mt][nt] = (f32x4){0.f, 0.f, 0.f, 0.f};

    for (int k0 = 0; k0 < K; k0 += 64) {
        // ---- stage via global_load_lds (1 KB per wave-issue, 16 issues)
        #pragma unroll
        for (int r = 0; r < 16; ++r) {
            const int row = r * 8 + lrow8;
            GLOAD_LDS(gp + (size_t)row * K + k0 + scol8,
                      lds + ldsbase + r * 1024 + 16 * lane);
        }
        __syncthreads();

        // ---- compute: 96 MFMA per wave (3-term compensated)
        #pragma unroll
        for (int kh = 0; kh < 2; ++kh) {
            short8 afh[4], afl[4];
            #pragma unroll
            for (int mt = 0; mt < 4; ++mt) {
                const int row = wm + 16 * mt + lq;
                const int off = row * 128 + ((kh * 64 + 16 * lg) ^ ((row & 7) << 4));
                afh[mt] = *(const short8*)(lds + off);
                afl[mt] = *(const short8*)(lds + 16384 + off);
            }
            #pragma unroll
            for (int nt = 0; nt < 4; ++nt) {
                const int row = wn + 16 * nt + lq;
                const int off = row * 128 + ((kh * 64 + 16 * lg) ^ ((row & 7) << 4));
                short8 bfh = *(const short8*)(lds + 32768 + off);
                short8 bfl = *(const short8*)(lds + 49152 + off);
                #pragma unroll
                for (int mt = 0; mt < 4; ++mt) {
                    acc[mt][nt] = MFMA16(afh[mt], bfh, acc[mt][nt], 0, 0, 0);
                    acc[mt][nt] = MFMA16(afh[mt], bfl, acc[mt][nt], 0, 0, 0);
                    acc[mt][nt] = MFMA16(afl[mt], bfh, acc[mt][nt], 0, 0, 0);
                }
            }
        }
        __syncthreads();
    }

    float gain = 0.f, ascv = 0.f, abiv = 0.f;
    if (MODE == 6) {
        gain = 0.25f * (*g0 + *g1 + *g2 + *g3);
        ascv = *asc;
        abiv = *abi;
    }

    #pragma unroll
    for (int nt = 0; nt < 4; ++nt) {
        const int n  = n0 + wn + 16 * nt + lq;
        const float bv = bias[n];
        #pragma unroll
        for (int mt = 0; mt < 4; ++mt) {
            #pragma unroll
            for (int j = 0; j < 4; ++j) {
                const int m = m0 + wm + 16 * mt + 4 * lg + j;
                float v = acc[mt][nt][j] + bv;
                if (RELU) v = fmaxf(v, 0.f);
                if (MODE == 0) {
                    C[(size_t)m * N + n] = v;
                } else if (MODE == 1) {
                    const int b = m >> 11, s = m & 2047;
                    const int h = n >> 6, d = n & 63;
                    C[((size_t)(b * PH + h) * PS + s) * PD + d] = v;
                } else if (MODE == 3) {
                    const int b = m >> 11, s = m & 2047;
                    const int h = n >> 6, d = n & 63;
                    const size_t idx = ((size_t)(b * PH + h) * PS + s) * PD + d;
                    unsigned short hh, ll;
                    split2(v, hh, ll);
                    Ohi[idx] = hh; Olo[idx] = ll;
                } else if (MODE == 4) {
                    const int b = m >> 11;
                    const int h = n >> 6, d = n & 63;
                    const int scol = (m & 2047 & ~63) + ((mt & 1) << 5)
                                   + (lg << 3) + ((mt >> 1) << 2) + j;
                    const size_t idx = ((size_t)(b * PH + h) * PD + d) * PS + scol;
                    unsigned short hh, ll;
                    split2(v, hh, ll);
                    Ohi[idx] = hh; Olo[idx] = ll;
                } else if (MODE == 5) {
                    const size_t idx = (size_t)m * N + n;
                    unsigned short hh, ll;
                    split2(v, hh, ll);
                    Ohi[idx] = hh; Olo[idx] = ll;
                } else { // MODE 6
                    const int b = m >> 11, s = m & 2047;
                    const int h = n >> 6, d = n & 63;
                    const float av = attn[((size_t)(b * PH + h) * PS + s) * PD + d];
                    const float o = (av * ascv + abiv) * (1.f + v * gain);
                    const size_t idx = (size_t)m * N + n;
                    unsigned short hh, ll;
                    split2(o, hh, ll);
                    Ohi[idx] = hh; Olo[idx] = ll;
                }
            }
        }
    }
}

// ---------------------------------------------------------------------------
// fp32-fed split-bf16 MFMA NT GEMM (fallback path, round-5 proven).
// ---------------------------------------------------------------------------
template<int MODE, bool RELU>
__global__ __launch_bounds__(256, 2)
void gemm_nt(const float* __restrict__ A, const float* __restrict__ Bw,
             const float* __restrict__ bias, float* __restrict__ C,
             unsigned short* __restrict__ Ohi, unsigned short* __restrict__ Olo,
             int M, int N, int K,
             const float* __restrict__ attn,
             const float* __restrict__ g0, const float* __restrict__ g1,
             const float* __restrict__ g2, const float* __restrict__ g3,
             const float* __restrict__ asc, const float* __restrict__ abi)
{
    __shared__ int4 ldsq[4096];
    char* const lds = (char*)ldsq;

    const int tid  = threadIdx.x;
    const int lane = tid & 63;
    const int w    = tid >> 6;
    const int lq   = lane & 15;
    const int lg   = lane >> 4;
    const int wm   = (w >> 1) * 64;
    const int wn   = (w & 1) * 64;
    const int m0   = blockIdx.x * 128;
    const int n0   = blockIdx.y * 128;

    const int irow = tid >> 3;
    const int ic8  = (tid & 7) * 8;
    const int woff = (ic8 * 2);

    f32x4 acc[4][4];
    #pragma unroll
    for (int mt = 0; mt < 4; ++mt)
        #pragma unroll
        for (int nt = 0; nt < 4; ++nt)
            acc[mt][nt] = (f32x4){0.f, 0.f, 0.f, 0.f};

    for (int k0 = 0; k0 < K; k0 += 64) {
        #pragma unroll
        for (int mat = 0; mat < 2; ++mat) {
            const float* const src = mat ? Bw : A;
            const int rbase = mat ? n0 : m0;
            const int pbase = mat ? 32768 : 0;
            #pragma unroll
            for (int r = 0; r < 4; ++r) {
                const int row = irow + 32 * r;
                const float* p = src + (size_t)(rbase + row) * K + k0 + ic8;
                float4 f0 = *(const float4*)p;
                float4 f1 = *(const float4*)(p + 4);
                short8 vh, vl;
                {
                    unsigned short h, l;
                    split2(f0.x, h, l); vh[0] = (short)h; vl[0] = (short)l;
                    split2(f0.y, h, l); vh[1] = (short)h; vl[1] = (short)l;
                    split2(f0.z, h, l); vh[2] = (short)h; vl[2] = (short)l;
                    split2(f0.w, h, l); vh[3] = (short)h; vl[3] = (short)l;
                    split2(f1.x, h, l); vh[4] = (short)h; vl[4] = (short)l;
                    split2(f1.y, h, l); vh[5] = (short)h; vl[5] = (short)l;
                    split2(f1.z, h, l); vh[6] = (short)h; vl[6] = (short)l;
                    split2(f1.w, h, l); vh[7] = (short)h; vl[7] = (short)l;
                }
                const int off = row * 128 + (woff ^ ((row & 7) << 4));
                *(short8*)(lds + pbase + off)         = vh;
                *(short8*)(lds + pbase + 16384 + off) = vl;
            }
        }
        __syncthreads();

        #pragma unroll
        for (int kh = 0; kh < 2; ++kh) {
            short8 afh[4], afl[4];
            #pragma unroll
            for (int mt = 0; mt < 4; ++mt) {
                const int row = wm + 16 * mt + lq;
                const int off = row * 128 + ((kh * 64 + 16 * lg) ^ ((row & 7) << 4));
                afh[mt] = *(const short8*)(lds + off);
                afl[mt] = *(const short8*)(lds + 16384 + off);
            }
            #pragma unroll
            for (int nt = 0; nt < 4; ++nt) {
                const int row = wn + 16 * nt + lq;
                const int off = row * 128 + ((kh * 64 + 16 * lg) ^ ((row & 7) << 4));
                short8 bfh = *(const short8*)(lds + 32768 + off);
                short8 bfl = *(const short8*)(lds + 49152 + off);
                #pragma unroll
                for (int mt = 0; mt < 4; ++mt) {
                    acc[mt][nt] = MFMA16(afh[mt], bfh, acc[mt][nt], 0, 0, 0);
                    acc[mt][nt] = MFMA16(afh[mt], bfl, acc[mt][nt], 0, 0, 0);
                    acc[mt][nt] = MFMA16(afl[mt], bfh, acc[mt][nt], 0, 0, 0);
                }
            }
        }
        __syncthreads();
    }

    float gain = 0.f, ascv = 0.f, abiv = 0.f;
    if (MODE == 2) {
        gain = 0.25f * (*g0 + *g1 + *g2 + *g3);
        ascv = *asc;
        abiv = *abi;
    }

    #pragma unroll
    for (int nt = 0; nt < 4; ++nt) {
        const int n  = n0 + wn + 16 * nt + lq;
        const float bv = bias[n];
        #pragma unroll
        for (int mt = 0; mt < 4; ++mt) {
            #pragma unroll
            for (int j = 0; j < 4; ++j) {
                const int m = m0 + wm + 16 * mt + 4 * lg + j;
                float v = acc[mt][nt][j] + bv;
                if (RELU) v = fmaxf(v, 0.f);
                if (MODE == 0) {
                    C[(size_t)m * N + n] = v;
                } else if (MODE == 1) {
                    const int b = m >> 11, s = m & 2047;
                    const int h = n >> 6, d = n & 63;
                    C[((size_t)(b * PH + h) * PS + s) * PD + d] = v;
                } else if (MODE == 3) {
                    const int b = m >> 11, s = m & 2047;
                    const int h = n >> 6, d = n & 63;
                    const size_t idx = ((size_t)(b * PH + h) * PS + s) * PD + d;
                    unsigned short hh, ll;
                    split2(v, hh, ll);
                    Ohi[idx] = hh; Olo[idx] = ll;
                } else if (MODE == 4) {
                    const int b = m >> 11;
                    const int h = n >> 6, d = n & 63;
                    const int scol = (m & 2047 & ~63) + ((mt & 1) << 5)
                                   + (lg << 3) + ((mt >> 1) << 2) + j;
                    const size_t idx = ((size_t)(b * PH + h) * PD + d) * PS + scol;
                    unsigned short hh, ll;
                    split2(v, hh, ll);
                    Ohi[idx] = hh; Olo[idx] = ll;
                } else { // MODE 2
                    const int b = m >> 11, s = m & 2047;
                    const int h = n >> 6, d = n & 63;
                    const float av = attn[((size_t)(b * PH + h) * PS + s) * PD + d];
                    C[(size_t)m * N + n] = (av * ascv + abiv) * (1.f + v * gain);
                }
            }
        }
    }
}

// ---------------------------------------------------------------------------
// MFMA flash attention v3: staging via global_load_lds (no reg staging,
// no spills). LDS layout identical to v2 (XOR-swizzled) — achieved by
// pre-swizzling the per-lane GLOBAL source address; read side unchanged.
// Wave w stages plane w (0:khi 1:klo 2:vthi 3:vtlo), 8x1KB issues.
// Double-buffered; prefetch next tile at top of loop; one barrier/tile.
// ---------------------------------------------------------------------------
__global__ __launch_bounds__(256, 2)
void flash_mfma(const float* qf,
                const unsigned short* __restrict__ khi,
                const unsigned short* __restrict__ klo,
                const unsigned short* __restrict__ vthi,
                const unsigned short* __restrict__ vtlo,
                float* attn)
{
    __shared__ int4 ldsv[4096];                    // 64 KB: 2 bufs x 4 planes x 8KB
    char* const ldsb = (char*)ldsv;

    const int tid  = threadIdx.x;
    const int lane = tid & 63;
    const int w    = tid >> 6;
    const int bh   = blockIdx.z * PH + blockIdx.y;
    const int lq   = lane & 15;
    const int lg   = lane >> 4;
    const int q0   = blockIdx.x * 128 + w * 32;

    const size_t kbase = (size_t)bh * PS * PD;   // K rows   [S][D]
    const size_t vbase = (size_t)bh * PD * PS;   // V^T rows [D][S] (permuted)

    // staging source for this wave
    const unsigned short* const gp =
        (w == 0) ? khi + kbase :
        (w == 1) ? klo + kbase :
        (w == 2) ? vthi + vbase :
                   vtlo + vbase;
    const bool isK = (w < 2);
    const int scol8 = (((lane & 7) ^ (lane >> 3)) << 3);   // pre-swizzled col
    const int lrow8 = lane >> 3;

    auto ISSUE = [&](int kt, int bufn) {
        #pragma unroll
        for (int r = 0; r < 8; ++r) {
            const int row = r * 8 + lrow8;
            const size_t goff = isK ? (size_t)(kt + row) * PD + scol8
                                    : (size_t)row * PS + kt + scol8;
            GLOAD_LDS(gp + goff,
                      ldsb + bufn * 32768 + w * 8192 + r * 1024 + 16 * lane);
        }
    };

    // ---- Q fragments (scale 1/8 folded in), 2 q-subtiles per wave
    short8 qh[2][2], ql[2][2];
    #pragma unroll
    for (int u = 0; u < 2; ++u) {
        const float* qp = qf + ((size_t)bh * PS + q0 + 16 * u + lq) * PD + 8 * lg;
        #pragma unroll
        for (int t = 0; t < 2; ++t)
            #pragma unroll
            for (int b = 0; b < 8; ++b) {
                float x = qp[t * 32 + b] * 0.125f;
                unsigned short h, l;
                split2(x, h, l);
                qh[u][t][b] = (short)h;
                ql[u][t][b] = (short)l;
            }
    }

    f32x4 ot[2][4];
    #pragma unroll
    for (int u = 0; u < 2; ++u)
        #pragma unroll
        for (int mt = 0; mt < 4; ++mt)
            ot[u][mt] = (f32x4){0.f, 0.f, 0.f, 0.f};
    float m_run[2] = {-3.0e38f, -3.0e38f};
    float l_run[2] = {0.f, 0.f};

    ISSUE(0, 0);
    __syncthreads();

    int buf = 0;
    for (int kti = 0; kti < PS / 64; ++kti) {
        const bool pf = (kti + 1 < PS / 64);
        if (pf) ISSUE((kti + 1) * 64, buf ^ 1);

        const char* const L = ldsb + buf * 32768;

        // ---- S^T tiles for both q-subtiles
        f32x4 st[2][4];
        #pragma unroll
        for (int mt = 0; mt < 4; ++mt) {
            const int row = 16 * mt + lq;
            const int swz = (row & 7) << 4;
            const char* kr = L + row * 128;
            short8 ah0 = *(const short8*)(kr + ((16 * lg) ^ swz));
            short8 ah1 = *(const short8*)(kr + ((64 + 16 * lg) ^ swz));
            short8 al0 = *(const short8*)(kr + 8192 + ((16 * lg) ^ swz));
            short8 al1 = *(const short8*)(kr + 8192 + ((64 + 16 * lg) ^ swz));
            #pragma unroll
            for (int u = 0; u < 2; ++u) {
                f32x4 acc = {0.f, 0.f, 0.f, 0.f};
                acc = MFMA16(ah0, qh[u][0], acc, 0, 0, 0);
                acc = MFMA16(ah1, qh[u][1], acc, 0, 0, 0);
                acc = MFMA16(ah0, ql[u][0], acc, 0, 0, 0);
                acc = MFMA16(ah1, ql[u][1], acc, 0, 0, 0);
                acc = MFMA16(al0, qh[u][0], acc, 0, 0, 0);
                acc = MFMA16(al1, qh[u][1], acc, 0, 0, 0);
                st[u][mt] = acc;
            }
        }

        // ---- online softmax + P pack, per q-subtile
        short8 pbh[2][2], pbl[2][2];
        #pragma unroll
        for (int u = 0; u < 2; ++u) {
            float pmax = -3.0e38f;
            #pragma unroll
            for (int mt = 0; mt < 4; ++mt)
                #pragma unroll
                for (int j = 0; j < 4; ++j)
                    pmax = fmaxf(pmax, st[u][mt][j]);
            pmax = fmaxf(pmax, __shfl_xor(pmax, 16));
            pmax = fmaxf(pmax, __shfl_xor(pmax, 32));
            float mnew = fmaxf(m_run[u], pmax);
            float corr = __expf(m_run[u] - mnew);
            float psum = 0.f;
            #pragma unroll
            for (int mt = 0; mt < 4; ++mt)
                #pragma unroll
                for (int j = 0; j < 4; ++j) {
                    float p = __expf(st[u][mt][j] - mnew);
                    psum += p;
                    st[u][mt][j] = p;
                }
            psum += __shfl_xor(psum, 16);
            psum += __shfl_xor(psum, 32);
            l_run[u] = l_run[u] * corr + psum;
            m_run[u] = mnew;
            #pragma unroll
            for (int mt = 0; mt < 4; ++mt)
                #pragma unroll
                for (int j = 0; j < 4; ++j)
                    ot[u][mt][j] *= corr;
            #pragma unroll
            for (int b = 0; b < 8; ++b) {
                const int mt0 = (b >> 2) << 1;
                unsigned short h0, l0, h1, l1;
                split2(st[u][mt0][b & 3], h0, l0);
                split2(st[u][mt0 + 1][b & 3], h1, l1);
                pbh[u][0][b] = (short)h0; pbl[u][0][b] = (short)l0;
                pbh[u][1][b] = (short)h1; pbl[u][1][b] = (short)l1;
            }
        }

        // ---- O^T += V^T . P^T
        #pragma unroll
        for (int t = 0; t < 2; ++t) {
            #pragma unroll
            for (int mt = 0; mt < 4; ++mt) {
                const int row = 16 * mt + lq;
                const int swz = (row & 7) << 4;
                const char* vr = L + 16384 + row * 128;
                short8 vh = *(const short8*)(vr + ((t * 64 + 16 * lg) ^ swz));
                short8 vl = *(const short8*)(vr + 8192 + ((t * 64 + 16 * lg) ^ swz));
                #pragma unroll
                for (int u = 0; u < 2; ++u) {
                    ot[u][mt] = MFMA16(vh, pbh[u][t], ot[u][mt], 0, 0, 0);
                    ot[u][mt] = MFMA16(vh, pbl[u][t], ot[u][mt], 0, 0, 0);
                    ot[u][mt] = MFMA16(vl, pbh[u][t], ot[u][mt], 0, 0, 0);
                }
            }
        }

        __syncthreads();        // drains prefetch vmcnt + protects LDS reuse
        buf ^= 1;
    }

    // ---- epilogue: attn[bh][q0+16u+lq][d], d = 16*mt + 4*lg + j
    #pragma unroll
    for (int u = 0; u < 2; ++u) {
        const float inv = 1.f / l_run[u];
        float* op = attn + ((size_t)bh * PS + q0 + 16 * u + lq) * PD + 4 * lg;
        #pragma unroll
        for (int mt = 0; mt < 4; ++mt) {
            float4 o;
            o.x = ot[u][mt][0] * inv; o.y = ot[u][mt][1] * inv;
            o.z = ot[u][mt][2] * inv; o.w = ot[u][mt][3] * inv;
            *(float4*)(op + 16 * mt) = o;
        }
    }
}

// ---------------------------------------------------------------------------
extern "C" void kernel_launch(void* const* d_in, const int* in_sizes, int n_in,
                              void* d_out, int out_size, void* d_ws, size_t ws_size,
                              hipStream_t stream)
{
    const float* query = (const float*)d_in[0];
    const float* Wq  = (const float*)d_in[1];  const float* bq  = (const float*)d_in[2];
    const float* Wk  = (const float*)d_in[3];  const float* bk  = (const float*)d_in[4];
    const float* Wv  = (const float*)d_in[5];  const float* bv  = (const float*)d_in[6];
    const float* Wo  = (const float*)d_in[7];  const float* bo  = (const float*)d_in[8];
    const float* Wm1 = (const float*)d_in[9];  const float* bm1 = (const float*)d_in[10];
    const float* Wm2 = (const float*)d_in[11]; const float* bm2 = (const float*)d_in[12];
    const float* dop = (const float*)d_in[13];
    const float* ser = (const float*)d_in[14];
    const float* nor = (const float*)d_in[15];
    const float* ach = (const float*)d_in[16];
    const float* asc = (const float*)d_in[17];
    const float* abi = (const float*)d_in[18];
    float* out = (float*)d_out;

    char* wsb = (char*)d_ws;
    // Common region (both paths), byte offsets:
    float*          qf32  = (float*)wsb;                         // [0, 32M)
    unsigned short* khi   = (unsigned short*)(wsb + (32u << 20));// [32M, 48M)
    unsigned short* klo   = khi + 8388608;                       // [48M, 64M)
    unsigned short* vthi  = (unsigned short*)(wsb + (64u << 20));// [64M, 80M)
    unsigned short* vtlo  = vthi + 8388608;                      // [80M, 96M)

    dim3 blk(256);
    const bool presplit = (ws_size >= 161480704ull);             // 154 MB

    if (presplit) {
        // planes layout
        unsigned short* h1hi  = (unsigned short*)(wsb + (96u << 20));
        unsigned short* h1lo  = h1hi + 2097152;                  // [100M,104M)
        unsigned short* qhi   = (unsigned short*)(wsb + (104u << 20));
        unsigned short* qlo   = qhi + 8388608;                   // [120M,136M)
        unsigned short* wqhi  = (unsigned short*)(wsb + (136u << 20));
        unsigned short* wqlo  = wqhi + 1048576;
        unsigned short* wkhi  = wqlo + 1048576;
        unsigned short* wklo  = wkhi + 1048576;
        unsigned short* wvhi  = wklo + 1048576;
        unsigned short* wvlo  = wvhi + 1048576;
        unsigned short* wohi  = wvlo + 1048576;
        unsigned short* wolo  = wohi + 1048576;                  // ends 152M
        unsigned short* wm1hi = (unsigned short*)(wsb + (152u << 20));
        unsigned short* wm1lo = wm1hi + 262144;                  // [152.5M,153M)
        unsigned short* wm2hi = (unsigned short*)(wsb + (153u << 20));
        unsigned short* wm2lo = wm2hi + 262144;                  // [153.5M,154M)
        unsigned short* afhi  = khi;                             // attnf over k planes
        unsigned short* aflo  = klo;

        // pre-split all fp32 operands to bf16 hi/lo planes
        split_mat<<<8192, blk, 0, stream>>>(query, qhi, qlo, 2097152);
        split_mat<<<1024, blk, 0, stream>>>(Wq, wqhi, wqlo, 262144);
        split_mat<<<1024, blk, 0, stream>>>(Wk, wkhi, wklo, 262144);
        split_mat<<<1024, blk, 0, stream>>>(Wv, wvhi, wvlo, 262144);
        split_mat<<<1024, blk, 0, stream>>>(Wo, wohi, wolo, 262144);
        split_mat<<<256,  blk, 0, stream>>>(Wm1, wm1hi, wm1lo, 65536);
        split_mat<<<256,  blk, 0, stream>>>(Wm2, wm2hi, wm2lo, 65536);

        gemm_pl<1, false><<<dim3(PM / 128, PE / 128), blk, 0, stream>>>(
            qhi, qlo, wqhi, wqlo, bq, qf32, nullptr, nullptr, PM, PE, PE,
            nullptr, nullptr, nullptr, nullptr, nullptr, nullptr, nullptr);
        gemm_pl<3, false><<<dim3(PM / 128, PE / 128), blk, 0, stream>>>(
            qhi, qlo, wkhi, wklo, bk, nullptr, khi, klo, PM, PE, PE,
            nullptr, nullptr, nullptr, nullptr, nullptr, nullptr, nullptr);
        gemm_pl<4, false><<<dim3(PM / 128, PE / 128), blk, 0, stream>>>(
            qhi, qlo, wvhi, wvlo, bv, nullptr, vthi, vtlo, PM, PE, PE,
            nullptr, nullptr, nullptr, nullptr, nullptr, nullptr, nullptr);
        gemm_pl<5, true><<<dim3(PM / 128, 256 / 128), blk, 0, stream>>>(
            qhi, qlo, wm1hi, wm1lo, bm1, nullptr, h1hi, h1lo, PM, 256, PE,
            nullptr, nullptr, nullptr, nullptr, nullptr, nullptr, nullptr);

        flash_mfma<<<dim3(PS / 128, PH, PB), blk, 0, stream>>>(
            qf32, khi, klo, vthi, vtlo, qf32);

        gemm_pl<6, false><<<dim3(PM / 128, PE / 128), blk, 0, stream>>>(
            h1hi, h1lo, wm2hi, wm2lo, bm2, nullptr, afhi, aflo, PM, PE, 256,
            qf32, dop, ser, nor, ach, asc, abi);
        gemm_pl<0, false><<<dim3(PM / 128, PE / 128), blk, 0, stream>>>(
            afhi, aflo, wohi, wolo, bo, out, nullptr, nullptr, PM, PE, PE,
            nullptr, nullptr, nullptr, nullptr, nullptr, nullptr, nullptr);
    } else {
        // fallback: round-5 fp32-fed engine (104 MB)
        float* h1    = (float*)(wsb + (96u << 20));
        float* attnf = (float*)khi;

        gemm_nt<1, false><<<dim3(PM / 128, PE / 128), blk, 0, stream>>>(
            query, Wq, bq, qf32, nullptr, nullptr, PM, PE, PE,
            nullptr, nullptr, nullptr, nullptr, nullptr, nullptr, nullptr);
        gemm_nt<3, false><<<dim3(PM / 128, PE / 128), blk, 0, stream>>>(
            query, Wk, bk, nullptr, khi, klo, PM, PE, PE,
            nullptr, nullptr, nullptr, nullptr, nullptr, nullptr, nullptr);
        gemm_nt<4, false><<<dim3(PM / 128, PE / 128), blk, 0, stream>>>(
            query, Wv, bv, nullptr, vthi, vtlo, PM, PE, PE,
            nullptr, nullptr, nullptr, nullptr, nullptr, nullptr, nullptr);
        gemm_nt<0, true><<<dim3(PM / 128, 256 / 128), blk, 0, stream>>>(
            query, Wm1, bm1, h1, nullptr, nullptr, PM, 256, PE,
            nullptr, nullptr, nullptr, nullptr, nullptr, nullptr, nullptr);

        flash_mfma<<<dim3(PS / 128, PH, PB), blk, 0, stream>>>(
            qf32, khi, klo, vthi, vtlo, qf32);

        gemm_nt<2, false><<<dim3(PM / 128, PE / 128), blk, 0, stream>>>(
            h1, Wm2, bm2, attnf, nullptr, nullptr, PM, PE, 256,
            qf32, dop, ser, nor, ach, asc, abi);
        gemm_nt<0, false><<<dim3(PM / 128, PE / 128), blk, 0, stream>>>(
            attnf, Wo, bo, out, nullptr, nullptr, PM, PE, PE,
            nullptr, nullptr, nullptr, nullptr, nullptr, nullptr, nullptr);
    }
}